// Round 15
// baseline (1535.085 us; speedup 1.0000x reference)
//
#include <hip/hip_runtime.h>
#include <math.h>

#define DEPTH_ 4
#define DIM_ 1024
#define HEADS_ 16
#define DHEAD_ 64
#define MLP_ 4096
#define CTX_ 1024
#define INNER_ 1024
#define B_ 4
#define N_ 1024
#define M_ 2048

typedef unsigned short u16;
typedef __attribute__((ext_vector_type(4))) unsigned short u16x4;
typedef __attribute__((ext_vector_type(8))) short bf16x8;
typedef __attribute__((ext_vector_type(4))) float f32x4;
typedef __attribute__((ext_vector_type(4))) int i32x4;

// Q pre-scale: 1/sqrt(64) * log2(e)  (softmax runs in exp2 domain)
#define SCQ 0.18033688011112042f

__device__ __forceinline__ u16 f2bf(float f) {
    unsigned u = __float_as_uint(f);
    return (u16)((u + 0x7fffu + ((u >> 16) & 1u)) >> 16);
}

__device__ __forceinline__ float bf2f(u16 v) {
    return __uint_as_float(((unsigned)v) << 16);
}

__device__ __forceinline__ float exp2_fast(float x) {
    float r;
    asm("v_exp_f32 %0, %1" : "=v"(r) : "v"(x));
    return r;
}

__device__ __forceinline__ float rcp_fast(float x) {
    float r;
    asm("v_rcp_f32 %0, %1" : "=v"(r) : "v"(x));
    return r;
}

__device__ __forceinline__ float max3f(float a, float b, float c) {
    float r;
    asm("v_max3_f32 %0, %1, %2, %3" : "=v"(r) : "v"(a), "v"(b), "v"(c));
    return r;
}

__device__ __forceinline__ unsigned cvt_pk_bf16(float lo, float hi) {
    unsigned r;
    asm("v_cvt_pk_bf16_f32 %0, %1, %2" : "=v"(r) : "v"(lo), "v"(hi));
    return r;
}

// gelu(x) = x * sigmoid(2*0.7978845608*(x + 0.044715 x^3)), exp2 domain
__device__ __forceinline__ float gelu_fast(float v) {
    float t = v + 0.044715f * v * v * v;
    float e = exp2_fast(-2.302221673f * t);
    return v * rcp_fast(1.0f + e);
}

// V^T kv-permutation (zero-shuffle PV): bijective within each 32-block; swaps
// the g(2b)/e2(1b) bit-fields so QK^T output regs are directly PV A-fragment.
__device__ __forceinline__ int kv_sigma(int kv) {
    return (kv & ~31) | (((kv >> 2) & 3) << 3) | (((kv >> 4) & 1) << 2) |
           (kv & 3);
}

#define GLOAD16(gp, sp)                                                        \
    __builtin_amdgcn_global_load_lds(                                          \
        (const __attribute__((address_space(1))) void*)(gp),                   \
        (__attribute__((address_space(3))) void*)(sp), 16, 0, 0)

// ---------------------------------------------------------------------------
// LayerNorm over bf16 residual stream xb (+ fused 4-delta residual add).
// MODE 0: y = LN(xb)                                   (xb unchanged)
// MODE 1: v = xb + d0+d1+d2+d3 + dbias; xb = v; y = LN(v)
// (d2 may alias y: same-row read-before-write within the owning thread.)
// ---------------------------------------------------------------------------
template <int MODE>
__global__ __launch_bounds__(256) void ln_res(
    u16* __restrict__ xb, const u16* d0, const u16* d1, const u16* d2,
    const u16* d3, const float* __restrict__ dbias,
    const float* __restrict__ g, const float* __restrict__ b, u16* y) {
    int row = blockIdx.x;
    u16x4 xv = ((const u16x4*)(xb + (size_t)row * DIM_))[threadIdx.x];
    float4 v = {bf2f(xv[0]), bf2f(xv[1]), bf2f(xv[2]), bf2f(xv[3])};
    if constexpr (MODE == 1) {
        u16x4 a0 = ((const u16x4*)(d0 + (size_t)row * DIM_))[threadIdx.x];
        u16x4 a1 = ((const u16x4*)(d1 + (size_t)row * DIM_))[threadIdx.x];
        u16x4 a2 = ((const u16x4*)(d2 + (size_t)row * DIM_))[threadIdx.x];
        u16x4 a3 = ((const u16x4*)(d3 + (size_t)row * DIM_))[threadIdx.x];
        float4 bb4 = ((const float4*)dbias)[threadIdx.x];
        v.x += bf2f(a0[0]) + bf2f(a1[0]) + bf2f(a2[0]) + bf2f(a3[0]) + bb4.x;
        v.y += bf2f(a0[1]) + bf2f(a1[1]) + bf2f(a2[1]) + bf2f(a3[1]) + bb4.y;
        v.z += bf2f(a0[2]) + bf2f(a1[2]) + bf2f(a2[2]) + bf2f(a3[2]) + bb4.z;
        v.w += bf2f(a0[3]) + bf2f(a1[3]) + bf2f(a2[3]) + bf2f(a3[3]) + bb4.w;
        u16x4 xo = {f2bf(v.x), f2bf(v.y), f2bf(v.z), f2bf(v.w)};
        ((u16x4*)(xb + (size_t)row * DIM_))[threadIdx.x] = xo;
    }
    float s  = v.x + v.y + v.z + v.w;
    float ss = v.x * v.x + v.y * v.y + v.z * v.z + v.w * v.w;
    #pragma unroll
    for (int off = 32; off; off >>= 1) {
        s  += __shfl_down(s, off);
        ss += __shfl_down(ss, off);
    }
    __shared__ float red[10];
    int wid = threadIdx.x >> 6, lane = threadIdx.x & 63;
    if (lane == 0) { red[wid] = s; red[4 + wid] = ss; }
    __syncthreads();
    if (threadIdx.x == 0) {
        float ts  = red[0] + red[1] + red[2] + red[3];
        float tss = red[4] + red[5] + red[6] + red[7];
        float mu  = ts * (1.0f / DIM_);
        float var = tss * (1.0f / DIM_) - mu * mu;
        red[8] = mu;
        red[9] = rsqrtf(var + 1e-5f);
    }
    __syncthreads();
    float mu = red[8], rs = red[9];
    float4 gg = ((const float4*)g)[threadIdx.x];
    float4 bb = ((const float4*)b)[threadIdx.x];
    u16x4 o;
    o[0] = f2bf((v.x - mu) * rs * gg.x + bb.x);
    o[1] = f2bf((v.y - mu) * rs * gg.y + bb.y);
    o[2] = f2bf((v.z - mu) * rs * gg.z + bb.z);
    o[3] = f2bf((v.w - mu) * rs * gg.w + bb.w);
    ((u16x4*)(y + (size_t)row * DIM_))[threadIdx.x] = o;
}

// Final residual: xout(fp32) = xb + d0+d1+d2+d3 + dbias
__global__ __launch_bounds__(256) void res_add(
    float* __restrict__ xout, const u16* __restrict__ xb,
    const u16* d0, const u16* d1, const u16* d2, const u16* d3,
    const float* __restrict__ dbias) {
    int row = blockIdx.x;
    u16x4 xv = ((const u16x4*)(xb + (size_t)row * DIM_))[threadIdx.x];
    u16x4 a0 = ((const u16x4*)(d0 + (size_t)row * DIM_))[threadIdx.x];
    u16x4 a1 = ((const u16x4*)(d1 + (size_t)row * DIM_))[threadIdx.x];
    u16x4 a2 = ((const u16x4*)(d2 + (size_t)row * DIM_))[threadIdx.x];
    u16x4 a3 = ((const u16x4*)(d3 + (size_t)row * DIM_))[threadIdx.x];
    float4 bb4 = ((const float4*)dbias)[threadIdx.x];
    float4 v;
    v.x = bf2f(xv[0]) + bf2f(a0[0]) + bf2f(a1[0]) + bf2f(a2[0]) +
          bf2f(a3[0]) + bb4.x;
    v.y = bf2f(xv[1]) + bf2f(a0[1]) + bf2f(a1[1]) + bf2f(a2[1]) +
          bf2f(a3[1]) + bb4.y;
    v.z = bf2f(xv[2]) + bf2f(a0[2]) + bf2f(a1[2]) + bf2f(a2[2]) +
          bf2f(a3[2]) + bb4.z;
    v.w = bf2f(xv[3]) + bf2f(a0[3]) + bf2f(a1[3]) + bf2f(a2[3]) +
          bf2f(a3[3]) + bb4.w;
    ((float4*)(xout + (size_t)row * DIM_))[threadIdx.x] = v;
}

// ---------------------------------------------------------------------------
// fp32 -> bf16 cast of two buffers in one dispatch (float4 per thread)
// ---------------------------------------------------------------------------
__global__ __launch_bounds__(256) void cast2_kernel(
    const float* __restrict__ in0, u16* __restrict__ out0, int n0,
    const float* __restrict__ in1, u16* __restrict__ out1) {
    int i = blockIdx.x * 256 + threadIdx.x;
    if (i < n0) {
        float4 v = ((const float4*)in0)[i];
        u16x4 o = {f2bf(v.x), f2bf(v.y), f2bf(v.z), f2bf(v.w)};
        ((u16x4*)out0)[i] = o;
    } else {
        int j = i - n0;
        float4 v = ((const float4*)in1)[j];
        u16x4 o = {f2bf(v.x), f2bf(v.y), f2bf(v.z), f2bf(v.w)};
        ((u16x4*)out1)[j] = o;
    }
}

// ---------------------------------------------------------------------------
// Fused weight prep for one layer: transpose+cast ALL 7 weight matrices
// ---------------------------------------------------------------------------
struct PrepArgs {
    const float* src[7];
    int K[7];
    int N[7];
    int dstOff[7];
    int tileCum[7];
};

__global__ __launch_bounds__(256) void prep_weights(PrepArgs a,
                                                    u16* __restrict__ wt) {
    __shared__ float tile[32][33];
    int bid = blockIdx.x;
    int wi = 0;
    while (bid >= a.tileCum[wi]) ++wi;
    int tbase = wi ? a.tileCum[wi - 1] : 0;
    int tid = bid - tbase;
    int Kd = a.K[wi], Nd = a.N[wi];
    int ntx = Nd >> 5;
    int bx = (tid % ntx) * 32;
    int by = (tid / ntx) * 32;
    const float* W = a.src[wi];
    u16* Wt = wt + a.dstOff[wi];

    int t = threadIdx.x;
    int kl = t >> 3, n4 = (t & 7) * 4;
    float4 v = *(const float4*)(W + (size_t)(by + kl) * Nd + bx + n4);
    tile[kl][n4 + 0] = v.x; tile[kl][n4 + 1] = v.y;
    tile[kl][n4 + 2] = v.z; tile[kl][n4 + 3] = v.w;
    __syncthreads();
    int nl = t >> 3, k4 = (t & 7) * 4;
    u16x4 o;
    #pragma unroll
    for (int j = 0; j < 4; ++j) o[j] = f2bf(tile[k4 + j][nl]);
    *(u16x4*)(Wt + (size_t)(bx + nl) * Kd + by + k4) = o;
}

// ---------------------------------------------------------------------------
// MFMA GEMM: 128x128 tile, BK=32, 4 waves 2x2, 3 LDS buffers, counted vmcnt,
// stage-after-barrier, T1 swizzle, T5 setprio, zero-conflict LDS swizzle.
// SPLITK==4 (EPI=0): chunk bz writes to {Cout, Cout+MN, CoutB, CoutC}[bz]
// (four EXPLICIT bf16 delta buffers, combined by the next ln_res/res_add).
// EPI: 0 = bf16 out (split-aware); 1 = +bias+gelu bf16;
//      4 = QKV: Q cols *SCQ -> big; K cols -> big; V cols ONLY -> vt
// ---------------------------------------------------------------------------
template <int EPI, int SPLITK>
__global__ __launch_bounds__(256, 3) void gemm_mfma3(
    const u16* __restrict__ A, const u16* __restrict__ Bt,
    const float* __restrict__ bias, void* __restrict__ Cout,
    void* __restrict__ CoutB, void* __restrict__ CoutC,
    u16* __restrict__ vt, int Mdim, int Ndim, int Kdim, int nx, int ny) {
    __shared__ __align__(16) u16 As[3][128 * 32];
    __shared__ __align__(16) u16 Bs[3][128 * 32];
    const int t = threadIdx.x;
    const int lane = t & 63, w = t >> 6;
    const int c = lane & 15, g = lane >> 4;
    const int wy = w >> 1, wx = w & 1;

    const int nwg = gridDim.x;
    const int wid = (blockIdx.x & 7) * (nwg >> 3) + (blockIdx.x >> 3);
    const int bx = wid % nx;
    const int by = (wid / nx) % ny;
    const int bz = wid / (nx * ny);
    const int m0 = by * 128, n0 = bx * 128;

    f32x4 acc[4][4] = {};

    const int srow = w * 32 + (lane >> 2);
    const int scb  = (((lane & 3) ^ ((srow >> 1) & 3)) * 8);
    const u16* Ag = A + (size_t)(m0 + srow) * Kdim + scb;
    const u16* Bg = Bt + (size_t)(n0 + srow) * Kdim + scb;

    auto stage = [&](int buf, int k0) {
        GLOAD16(Ag + k0, &As[buf][w * 1024]);
        GLOAD16(Ag + k0 + (size_t)16 * Kdim, &As[buf][w * 1024 + 512]);
        GLOAD16(Bg + k0, &Bs[buf][w * 1024]);
        GLOAD16(Bg + k0 + (size_t)16 * Kdim, &Bs[buf][w * 1024 + 512]);
    };
    const int rsw = (c >> 1) & 3;
    auto compute = [&](int buf) {
        bf16x8 a[4], b[4];
        #pragma unroll
        for (int i = 0; i < 4; ++i)
            a[i] = *(const bf16x8*)&As[buf][(wy * 64 + i * 16 + c) * 32 +
                                            ((g ^ rsw) * 8)];
        #pragma unroll
        for (int j = 0; j < 4; ++j)
            b[j] = *(const bf16x8*)&Bs[buf][(wx * 64 + j * 16 + c) * 32 +
                                            ((g ^ rsw) * 8)];
        __builtin_amdgcn_s_setprio(1);
        #pragma unroll
        for (int i = 0; i < 4; ++i)
            #pragma unroll
            for (int j = 0; j < 4; ++j)
                acc[i][j] = __builtin_amdgcn_mfma_f32_16x16x32_bf16(
                    a[i], b[j], acc[i][j], 0, 0, 0);
        __builtin_amdgcn_s_setprio(0);
    };

    const int kchunk = Kdim / SPLITK;
    const int kbeg = bz * kchunk;
    const int nsteps = kchunk / 32;

    stage(0, kbeg);
    stage(1, kbeg + 32);
    int cb = 0, sb = 2;
    for (int s = 0; s < nsteps; ++s) {
        if (s + 1 < nsteps)
            asm volatile("s_waitcnt vmcnt(4)" ::: "memory");
        else
            asm volatile("s_waitcnt vmcnt(0)" ::: "memory");
        __builtin_amdgcn_s_barrier();
        if (s + 2 < nsteps) {
            stage(sb, kbeg + (s + 2) * 32);
            sb = (sb == 2) ? 0 : sb + 1;
        }
        compute(cb);
        cb = (cb == 2) ? 0 : cb + 1;
    }

    u16* outp = nullptr;
    if constexpr (EPI == 0) {
        if constexpr (SPLITK == 1) {
            outp = (u16*)Cout;
        } else {
            const size_t MN = (size_t)Mdim * Ndim;
            outp = (bz == 0)   ? (u16*)Cout
                   : (bz == 1) ? (u16*)Cout + MN
                   : (bz == 2) ? (u16*)CoutB
                               : (u16*)CoutC;
        }
    }

    #pragma unroll
    for (int i = 0; i < 4; ++i) {
        int row0 = m0 + wy * 64 + i * 16 + g * 4;
        #pragma unroll
        for (int j = 0; j < 4; ++j) {
            int col = n0 + wx * 64 + j * 16 + c;
            u16x4 o4;
            #pragma unroll
            for (int r = 0; r < 4; ++r) {
                float v = acc[i][j][r];
                size_t idx = (size_t)(row0 + r) * Ndim + col;
                if constexpr (EPI == 0) {
                    outp[idx] = f2bf(v);
                } else if constexpr (EPI == 4) {
                    if (col < 1024) {
                        ((u16*)Cout)[idx] = f2bf(v * SCQ);
                    } else if (col < 2048) {
                        ((u16*)Cout)[idx] = f2bf(v);
                    } else {
                        o4[r] = f2bf(v);  // V: only vt is written
                    }
                } else if constexpr (EPI == 1) {
                    v += bias[col];
                    ((u16*)Cout)[idx] = f2bf(gelu_fast(v));
                }
            }
            if constexpr (EPI == 4) {
                if (n0 + wx * 64 + j * 16 >= 2048) {
                    int hh = (col - 2048) >> 6;
                    int dd = col & 63;
                    int bi = row0 / 1024;
                    int kv = row0 % 1024;
                    int kvs = kv_sigma(kv);
                    *(u16x4*)&vt[(((size_t)bi * HEADS_ + hh) * 64 + dd) * 1024 +
                                 kvs] = o4;
                }
            }
        }
    }
}

// ---------------------------------------------------------------------------
// Dual GEMM: Wkv (1024 tiles) + Wq (256 tiles) on one 1280-block grid.
// K cols -> big; V cols ONLY -> vt (kv-permuted); Wq output scaled by SCQ.
// ---------------------------------------------------------------------------
__global__ __launch_bounds__(256, 3) void gemm_dual(
    const u16* __restrict__ Akv, const u16* __restrict__ Btkv,
    u16* __restrict__ Ckv, u16* __restrict__ vt,
    const u16* __restrict__ Aq, const u16* __restrict__ Btq,
    u16* __restrict__ Cq) {
    __shared__ __align__(16) u16 As[3][128 * 32];
    __shared__ __align__(16) u16 Bs[3][128 * 32];
    const int t = threadIdx.x;
    const int lane = t & 63, w = t >> 6;
    const int c = lane & 15, g = lane >> 4;
    const int wy = w >> 1, wx = w & 1;
    const int Kdim = 1024;

    const int nwg = gridDim.x;  // 1280
    const int wid = (blockIdx.x & 7) * (nwg >> 3) + (blockIdx.x >> 3);
    const bool pkv = wid < 1024;
    const u16* A;
    const u16* Bt;
    u16* Cc;
    int Ndim, bx, by;
    if (pkv) {
        A = Akv; Bt = Btkv; Cc = Ckv; Ndim = 2048;
        bx = wid & 15; by = wid >> 4;
    } else {
        int w2 = wid - 1024;
        A = Aq; Bt = Btq; Cc = Cq; Ndim = 1024;
        bx = w2 & 7; by = w2 >> 3;
    }
    const int m0 = by * 128, n0 = bx * 128;

    f32x4 acc[4][4] = {};

    const int srow = w * 32 + (lane >> 2);
    const int scb  = (((lane & 3) ^ ((srow >> 1) & 3)) * 8);
    const u16* Ag = A + (size_t)(m0 + srow) * Kdim + scb;
    const u16* Bg = Bt + (size_t)(n0 + srow) * Kdim + scb;

    auto stage = [&](int buf, int k0) {
        GLOAD16(Ag + k0, &As[buf][w * 1024]);
        GLOAD16(Ag + k0 + (size_t)16 * Kdim, &As[buf][w * 1024 + 512]);
        GLOAD16(Bg + k0, &Bs[buf][w * 1024]);
        GLOAD16(Bg + k0 + (size_t)16 * Kdim, &Bs[buf][w * 1024 + 512]);
    };
    const int rsw = (c >> 1) & 3;
    auto compute = [&](int buf) {
        bf16x8 a[4], b[4];
        #pragma unroll
        for (int i = 0; i < 4; ++i)
            a[i] = *(const bf16x8*)&As[buf][(wy * 64 + i * 16 + c) * 32 +
                                            ((g ^ rsw) * 8)];
        #pragma unroll
        for (int j = 0; j < 4; ++j)
            b[j] = *(const bf16x8*)&Bs[buf][(wx * 64 + j * 16 + c) * 32 +
                                            ((g ^ rsw) * 8)];
        __builtin_amdgcn_s_setprio(1);
        #pragma unroll
        for (int i = 0; i < 4; ++i)
            #pragma unroll
            for (int j = 0; j < 4; ++j)
                acc[i][j] = __builtin_amdgcn_mfma_f32_16x16x32_bf16(
                    a[i], b[j], acc[i][j], 0, 0, 0);
        __builtin_amdgcn_s_setprio(0);
    };

    stage(0, 0);
    stage(1, 32);
    int cb = 0, sb = 2;
    const int nsteps = 32;
    for (int s = 0; s < nsteps; ++s) {
        if (s + 1 < nsteps)
            asm volatile("s_waitcnt vmcnt(4)" ::: "memory");
        else
            asm volatile("s_waitcnt vmcnt(0)" ::: "memory");
        __builtin_amdgcn_s_barrier();
        if (s + 2 < nsteps) {
            stage(sb, (s + 2) * 32);
            sb = (sb == 2) ? 0 : sb + 1;
        }
        compute(cb);
        cb = (cb == 2) ? 0 : cb + 1;
    }

    #pragma unroll
    for (int i = 0; i < 4; ++i) {
        int row0 = m0 + wy * 64 + i * 16 + g * 4;
        #pragma unroll
        for (int j = 0; j < 4; ++j) {
            int col = n0 + wx * 64 + j * 16 + c;
            u16x4 o4;
            #pragma unroll
            for (int r = 0; r < 4; ++r) {
                float v = acc[i][j][r];
                size_t idx = (size_t)(row0 + r) * Ndim + col;
                if (pkv) {
                    u16 bv = f2bf(v);
                    if (col < 1024) Cc[idx] = bv;  // K only; V region dead
                    o4[r] = bv;
                } else {
                    Cc[idx] = f2bf(v * SCQ);
                }
            }
            if (pkv && (n0 + wx * 64 + j * 16 >= 1024)) {
                int hh = (col - 1024) >> 6;
                int dd = col & 63;
                int bi = row0 / 2048;
                int kv = row0 % 2048;
                int kvs = kv_sigma(kv);
                *(u16x4*)&vt[(((size_t)bi * HEADS_ + hh) * 64 + dd) * 2048 +
                             kvs] = o4;
            }
        }
    }
}

// ---------------------------------------------------------------------------
// MFMA flash attention v7 (R13-proven): TWO 64-row q-groups per block share
// each staged K/V tile; grid 512 blocks; 3-buffer counted-vmcnt pipeline;
// zero-shuffle PV + ones-column lr; v_max3 tree; defer-max; exp2-domain
// softmax; cvt_pk packing; XCD swizzle.
// ---------------------------------------------------------------------------
template <int KLEN, int IS_SA>
__global__ __launch_bounds__(256) void attn_mfma3(
    const u16* __restrict__ Qsrc, const u16* __restrict__ Ksrc,
    const u16* __restrict__ Vtg, const int* __restrict__ mask,
    u16* __restrict__ O) {
    constexpr int QSTR = IS_SA ? 3 * INNER_ : INNER_;
    constexpr int KSTR = IS_SA ? 3 * INNER_ : 2 * INNER_;
    constexpr int KOFF = IS_SA ? INNER_ : 0;

    __shared__ __align__(16) u16 Ks[3][64 * 64];
    __shared__ __align__(16) u16 Vs[3][64 * 64];

    const int t = threadIdx.x;
    const int lane = t & 63, w = t >> 6;
    const int c = lane & 15, g = lane >> 4;

    const int nwg = gridDim.x;  // 512
    const int wid = (blockIdx.x & 7) * (nwg >> 3) + (blockIdx.x >> 3);
    const int qb = wid & 7;
    const int h  = (wid >> 3) & 15;
    const int bb = wid >> 7;
    const int q0 = qb * 128;
    const int kvbase = bb * KLEN;

    const u16* qp0 =
        Qsrc + (size_t)(bb * N_ + q0 + w * 16 + c) * QSTR + h * 64 + g * 8;
    const u16* qp1 = qp0 + (size_t)64 * QSTR;
    bf16x8 qf0[2], qf1[2];
    qf0[0] = *(const bf16x8*)qp0;
    qf0[1] = *(const bf16x8*)(qp0 + 32);
    qf1[0] = *(const bf16x8*)qp1;
    qf1[1] = *(const bf16x8*)(qp1 + 32);

    const int sl_r = lane >> 3;
    const int scol = ((lane & 7) ^ sl_r) * 8;
    const int r0 = w * 16, r1 = w * 16 + 8;
    const u16* kp0 = Ksrc + (size_t)(kvbase + r0 + sl_r) * KSTR + KOFF +
                     h * 64 + scol;
    const u16* kp1 = Ksrc + (size_t)(kvbase + r1 + sl_r) * KSTR + KOFF +
                     h * 64 + scol;
    const u16* vp0 =
        Vtg + ((size_t)(bb * HEADS_ + h) * 64 + r0 + sl_r) * KLEN + scol;
    const u16* vp1 =
        Vtg + ((size_t)(bb * HEADS_ + h) * 64 + r1 + sl_r) * KLEN + scol;
    const int* mp = mask + bb * N_ + lane;

    auto stageKV = [&](int buf) {
        GLOAD16(kp0, &Ks[buf][r0 * 64]);
        GLOAD16(kp1, &Ks[buf][r1 * 64]);
        GLOAD16(vp0, &Vs[buf][r0 * 64]);
        GLOAD16(vp1, &Vs[buf][r1 * 64]);
        kp0 += (size_t)64 * KSTR;
        kp1 += (size_t)64 * KSTR;
        vp0 += 64;
        vp1 += 64;
    };

    f32x4 o0[4] = {}, o1[4] = {};
    f32x4 oL0 = {}, oL1 = {};
    float mr0 = -1e30f, mr1 = -1e30f;
    const i32x4 onesI = {0x3F803F80, 0x3F803F80, 0x3F803F80, 0x3F803F80};
    const bf16x8 ones = *(const bf16x8*)&onesI;
    constexpr int NT = KLEN / 64;

    stageKV(0);
    stageKV(1);
    int cb = 0, sb = 2;

    for (int kt = 0; kt < NT; ++kt) {
        if (kt + 1 < NT)
            asm volatile("s_waitcnt vmcnt(4)" ::: "memory");
        else
            asm volatile("s_waitcnt vmcnt(0)" ::: "memory");
        __builtin_amdgcn_s_barrier();
        int mbit = 1;
        if constexpr (IS_SA) {
            mbit = *mp;
            mp += 64;
        }
        if (kt + 2 < NT) {
            stageKV(sb);
            sb = (sb == 2) ? 0 : sb + 1;
        }

        // S^T = K Q^T for both q-groups; K fragment loaded once
        f32x4 sv0[4] = {}, sv1[4] = {};
        #pragma unroll
        for (int kvb = 0; kvb < 4; ++kvb) {
            #pragma unroll
            for (int f = 0; f < 2; ++f) {
                bf16x8 kf = *(const bf16x8*)&Ks[cb][(kvb * 16 + c) * 64 +
                                                    (((g + 4 * f) ^ (c & 7)) * 8)];
                sv0[kvb] = __builtin_amdgcn_mfma_f32_16x16x32_bf16(
                    kf, qf0[f], sv0[kvb], 0, 0, 0);
                sv1[kvb] = __builtin_amdgcn_mfma_f32_16x16x32_bf16(
                    kf, qf1[f], sv1[kvb], 0, 0, 0);
            }
        }

        if constexpr (IS_SA) {
            unsigned long long ball = __ballot(mbit != 0);
            if (ball != ~0ull) {
                float negm_reg = mbit ? 0.f : 2.0e10f;
                #pragma unroll
                for (int kvb = 0; kvb < 4; ++kvb)
                    #pragma unroll
                    for (int r = 0; r < 4; ++r) {
                        float nm = __shfl(negm_reg, kvb * 16 + g * 4 + r);
                        sv0[kvb][r] -= nm;
                        sv1[kvb][r] -= nm;
                    }
            }
        }

        // local max per group (max3 tree)
        float a0 = max3f(sv0[0][0], sv0[0][1], sv0[0][2]);
        float a1 = max3f(sv0[0][3], sv0[1][0], sv0[1][1]);
        float a2 = max3f(sv0[1][2], sv0[1][3], sv0[2][0]);
        float a3 = max3f(sv0[2][1], sv0[2][2], sv0[2][3]);
        float a4 = max3f(sv0[3][0], sv0[3][1], sv0[3][2]);
        float tm0 = fmaxf(max3f(a0, a1, a2), max3f(a3, a4, sv0[3][3]));
        float b0 = max3f(sv1[0][0], sv1[0][1], sv1[0][2]);
        float b1 = max3f(sv1[0][3], sv1[1][0], sv1[1][1]);
        float b2 = max3f(sv1[1][2], sv1[1][3], sv1[2][0]);
        float b3 = max3f(sv1[2][1], sv1[2][2], sv1[2][3]);
        float b4 = max3f(sv1[3][0], sv1[3][1], sv1[3][2]);
        float tm1 = fmaxf(max3f(b0, b1, b2), max3f(b3, b4, sv1[3][3]));

        if (!__all(fmaxf(tm0 - mr0, tm1 - mr1) <= 8.0f)) {  // rare rescale
            float t0 = fmaxf(tm0, __shfl_xor(tm0, 16));
            t0 = fmaxf(t0, __shfl_xor(t0, 32));
            float t1 = fmaxf(tm1, __shfl_xor(tm1, 16));
            t1 = fmaxf(t1, __shfl_xor(t1, 32));
            float mn0 = fmaxf(mr0, t0), mn1 = fmaxf(mr1, t1);
            float c0 = exp2_fast(mr0 - mn0), c1 = exp2_fast(mr1 - mn1);
            mr0 = mn0; mr1 = mn1;
            float c0O[4], c1O[4];
            #pragma unroll
            for (int r = 0; r < 4; ++r) {
                c0O[r] = __shfl(c0, g * 4 + r);
                c1O[r] = __shfl(c1, g * 4 + r);
            }
            #pragma unroll
            for (int db = 0; db < 4; ++db)
                #pragma unroll
                for (int r = 0; r < 4; ++r) {
                    o0[db][r] *= c0O[r];
                    o1[db][r] *= c1O[r];
                }
            #pragma unroll
            for (int r = 0; r < 4; ++r) {
                oL0[r] *= c0O[r];
                oL1[r] *= c1O[r];
            }
        }

        #pragma unroll
        for (int kvb = 0; kvb < 4; ++kvb)
            #pragma unroll
            for (int r = 0; r < 4; ++r) {
                sv0[kvb][r] = exp2_fast(sv0[kvb][r] - mr0);
                sv1[kvb][r] = exp2_fast(sv1[kvb][r] - mr1);
            }

        unsigned pk0[4][2], pk1[4][2];
        #pragma unroll
        for (int kvb = 0; kvb < 4; ++kvb)
            #pragma unroll
            for (int j = 0; j < 2; ++j) {
                pk0[kvb][j] = cvt_pk_bf16(sv0[kvb][2 * j], sv0[kvb][2 * j + 1]);
                pk1[kvb][j] = cvt_pk_bf16(sv1[kvb][2 * j], sv1[kvb][2 * j + 1]);
            }

        // zero-shuffle PV + ones-column row-sum; V fragment loaded once
        #pragma unroll
        for (int pv = 0; pv < 2; ++pv) {
            i32x4 tw0 = {(int)pk0[2 * pv][0], (int)pk0[2 * pv][1],
                         (int)pk0[2 * pv + 1][0], (int)pk0[2 * pv + 1][1]};
            i32x4 tw1 = {(int)pk1[2 * pv][0], (int)pk1[2 * pv][1],
                         (int)pk1[2 * pv + 1][0], (int)pk1[2 * pv + 1][1]};
            bf16x8 pa0 = *(bf16x8*)&tw0;
            bf16x8 pa1 = *(bf16x8*)&tw1;
            oL0 = __builtin_amdgcn_mfma_f32_16x16x32_bf16(pa0, ones, oL0, 0, 0, 0);
            oL1 = __builtin_amdgcn_mfma_f32_16x16x32_bf16(pa1, ones, oL1, 0, 0, 0);
            #pragma unroll
            for (int db = 0; db < 4; ++db) {
                bf16x8 vf = *(const bf16x8*)&Vs[cb][(db * 16 + c) * 64 +
                                                    (((g + 4 * pv) ^ (c & 7)) * 8)];
                o0[db] = __builtin_amdgcn_mfma_f32_16x16x32_bf16(pa0, vf,
                                                                 o0[db], 0, 0, 0);
                o1[db] = __builtin_amdgcn_mfma_f32_16x16x32_bf16(pa1, vf,
                                                                 o1[db], 0, 0, 0);
            }
        }
        cb = (cb == 2) ? 0 : cb + 1;
    }

    float i0[4], i1[4];
    #pragma unroll
    for (int r = 0; r < 4; ++r) {
        i0[r] = rcp_fast(oL0[r]);
        i1[r] = rcp_fast(oL1[r]);
    }
    #pragma unroll
    for (int db = 0; db < 4; ++db)
        #pragma unroll
        for (int r = 0; r < 4; ++r) {
            size_t idx =
                (size_t)(bb * N_ + q0 + w * 16 + g * 4 + r) * INNER_ +
                h * 64 + db * 16 + c;
            O[idx] = f2bf(o0[db][r] * i0[r]);
            O[idx + (size_t)64 * INNER_] = f2bf(o1[db][r] * i1[r]);
        }
}

// ---------------------------------------------------------------------------
extern "C" void kernel_launch(void* const* d_in, const int* in_sizes, int n_in,
                              void* d_out, int out_size, void* d_ws,
                              size_t ws_size, hipStream_t stream) {
    const float* x     = (const float*)d_in[0];
    const float* ctx   = (const float*)d_in[1];
    const int*   mask  = (const int*)d_in[2];
    const float* ln_g  = (const float*)d_in[3];
    const float* ln_b  = (const float*)d_in[4];
    const float* Wqkv  = (const float*)d_in[5];
    const float* Wo_sa = (const float*)d_in[6];
    const float* bo_sa = (const float*)d_in[7];
    const float* Wkv   = (const float*)d_in[8];
    const float* Wq    = (const float*)d_in[9];
    const float* Wo_ca = (const float*)d_in[10];
    const float* bo_ca = (const float*)d_in[11];
    const float* W1    = (const float*)d_in[12];
    const float* b1    = (const float*)d_in[13];
    const float* W2    = (const float*)d_in[14];
    const float* b2    = (const float*)d_in[15];
    float* xout = (float*)d_out;

    char* ws = (char*)d_ws;
    u16* lnout = (u16*)ws;                        // 8MB (attn out, W2 d2)
    u16* big   = (u16*)(ws + (8ull << 20));       // 32MB: qkv/kv/h1, Wo d2+d3
    u16* qca   = (u16*)(ws + (40ull << 20));      // 8MB (CA Q, W2 d3)
    u16* ctxb  = (u16*)(ws + (48ull << 20));      // 16MB
    u16* wt    = (u16*)(ws + (64ull << 20));      // 32MB: transposed wts
    u16* xb    = (u16*)(ws + (96ull << 20));      // 8MB: bf16 residual stream
    u16* R1    = (u16*)(ws + (104ull << 20));     // 16MB: vt | d0+d1
    u16* aout  = lnout;

    // wt sub-offsets (elements)
    const int O_QKV = 0;
    const int O_WOSA = 3145728;
    const int O_WQ   = 4194304;
    const int O_WKV  = 5242880;
    const int O_WOCA = 7340032;
    const int O_W1   = 8388608;
    const int O_W2   = 12582912;

    const int ROWS = B_ * N_;    // 4096
    const int HALF = ROWS * DIM_;
    dim3 blk(256);

    // one dispatch casts both ctx (8M f32) and x (4M f32)
    cast2_kernel<<<(B_ * M_ * CTX_ + B_ * N_ * DIM_) / 1024, blk, 0, stream>>>(
        ctx, ctxb, B_ * M_ * CTX_ / 4, x, xb);

    for (int i = 0; i < DEPTH_; ++i) {
        const float* g  = ln_g + (size_t)(i * 3) * DIM_;
        const float* bb = ln_b + (size_t)(i * 3) * DIM_;

        PrepArgs pa;
        pa.src[0] = Wqkv  + (size_t)i * DIM_ * 3 * INNER_;
        pa.src[1] = Wo_sa + (size_t)i * INNER_ * DIM_;
        pa.src[2] = Wq    + (size_t)i * DIM_ * INNER_;
        pa.src[3] = Wkv   + (size_t)i * CTX_ * 2 * INNER_;
        pa.src[4] = Wo_ca + (size_t)i * INNER_ * DIM_;
        pa.src[5] = W1    + (size_t)i * DIM_ * MLP_;
        pa.src[6] = W2    + (size_t)i * MLP_ * DIM_;
        int Ks_[7] = {1024, 1024, 1024, 1024, 1024, 1024, 4096};
        int Ns_[7] = {3072, 1024, 1024, 2048, 1024, 4096, 1024};
        int Of_[7] = {O_QKV, O_WOSA, O_WQ, O_WKV, O_WOCA, O_W1, O_W2};
        int cum = 0;
        for (int k = 0; k < 7; ++k) {
            pa.K[k] = Ks_[k]; pa.N[k] = Ns_[k]; pa.dstOff[k] = Of_[k];
            cum += (Ks_[k] / 32) * (Ns_[k] / 32);
            pa.tileCum[k] = cum;
        }
        prep_weights<<<cum, blk, 0, stream>>>(pa, wt);

        // ---- self-attention ----
        if (i == 0)
            ln_res<0><<<ROWS, blk, 0, stream>>>(xb, nullptr, nullptr, nullptr,
                                                nullptr, nullptr, g, bb,
                                                lnout);
        else
            ln_res<1><<<ROWS, blk, 0, stream>>>(xb, R1, R1 + HALF, lnout, qca,
                                                b2 + (size_t)(i - 1) * DIM_,
                                                g, bb, lnout);
        gemm_mfma3<4, 1><<<24 * 32, blk, 0, stream>>>(
            lnout, wt + O_QKV, nullptr, big, nullptr, nullptr, R1, ROWS,
            3 * INNER_, DIM_, 24, 32);
        attn_mfma3<N_, 1><<<512, blk, 0, stream>>>(big, big, R1, mask, aout);
        gemm_mfma3<0, 4><<<8 * 32 * 4, blk, 0, stream>>>(
            aout, wt + O_WOSA, nullptr, R1, big, big + HALF, nullptr, ROWS,
            DIM_, INNER_, 8, 32);

        // ---- cross-attention ----
        ln_res<1><<<ROWS, blk, 0, stream>>>(xb, R1, R1 + HALF, big,
                                            big + HALF,
                                            bo_sa + (size_t)i * DIM_,
                                            g + DIM_, bb + DIM_, lnout);
        gemm_dual<<<1280, blk, 0, stream>>>(ctxb, wt + O_WKV, big, R1,
                                            lnout, wt + O_WQ, qca);
        attn_mfma3<M_, 0><<<512, blk, 0, stream>>>(qca, big, R1, mask, aout);
        gemm_mfma3<0, 4><<<8 * 32 * 4, blk, 0, stream>>>(
            aout, wt + O_WOCA, nullptr, R1, big, big + HALF, nullptr, ROWS,
            DIM_, INNER_, 8, 32);

        // ---- feed-forward ----
        ln_res<1><<<ROWS, blk, 0, stream>>>(xb, R1, R1 + HALF, big,
                                            big + HALF,
                                            bo_ca + (size_t)i * DIM_,
                                            g + 2 * DIM_, bb + 2 * DIM_,
                                            lnout);
        gemm_mfma3<1, 1><<<32 * 32, blk, 0, stream>>>(
            lnout, wt + O_W1, b1 + (size_t)i * MLP_, big, nullptr, nullptr,
            nullptr, ROWS, MLP_, DIM_, 32, 32);
        gemm_mfma3<0, 4><<<8 * 32 * 4, blk, 0, stream>>>(
            big, wt + O_W2, nullptr, R1, lnout, qca, nullptr, ROWS, DIM_,
            MLP_, 8, 32);
    }
    res_add<<<ROWS, blk, 0, stream>>>(xout, xb, R1, R1 + HALF, lnout, qca,
                                      b2 + (size_t)(DEPTH_ - 1) * DIM_);
}

// Round 16
// 1466.423 us; speedup vs baseline: 1.0468x; 1.0468x over previous
//
#include <hip/hip_runtime.h>
#include <math.h>

#define DEPTH_ 4
#define DIM_ 1024
#define HEADS_ 16
#define DHEAD_ 64
#define MLP_ 4096
#define CTX_ 1024
#define INNER_ 1024
#define B_ 4
#define N_ 1024
#define M_ 2048

typedef unsigned short u16;
typedef __attribute__((ext_vector_type(4))) unsigned short u16x4;
typedef __attribute__((ext_vector_type(8))) short bf16x8;
typedef __attribute__((ext_vector_type(4))) float f32x4;
typedef __attribute__((ext_vector_type(4))) int i32x4;

// Q pre-scale: 1/sqrt(64) * log2(e)  (softmax runs in exp2 domain)
#define SCQ 0.18033688011112042f

__device__ __forceinline__ u16 f2bf(float f) {
    unsigned u = __float_as_uint(f);
    return (u16)((u + 0x7fffu + ((u >> 16) & 1u)) >> 16);
}

__device__ __forceinline__ float bf2f(u16 v) {
    return __uint_as_float(((unsigned)v) << 16);
}

__device__ __forceinline__ float exp2_fast(float x) {
    float r;
    asm("v_exp_f32 %0, %1" : "=v"(r) : "v"(x));
    return r;
}

__device__ __forceinline__ float rcp_fast(float x) {
    float r;
    asm("v_rcp_f32 %0, %1" : "=v"(r) : "v"(x));
    return r;
}

__device__ __forceinline__ float max3f(float a, float b, float c) {
    float r;
    asm("v_max3_f32 %0, %1, %2, %3" : "=v"(r) : "v"(a), "v"(b), "v"(c));
    return r;
}

__device__ __forceinline__ unsigned cvt_pk_bf16(float lo, float hi) {
    unsigned r;
    asm("v_cvt_pk_bf16_f32 %0, %1, %2" : "=v"(r) : "v"(lo), "v"(hi));
    return r;
}

// gelu(x) = x * sigmoid(2*0.7978845608*(x + 0.044715 x^3)), exp2 domain
__device__ __forceinline__ float gelu_fast(float v) {
    float t = v + 0.044715f * v * v * v;
    float e = exp2_fast(-2.302221673f * t);
    return v * rcp_fast(1.0f + e);
}

// V^T kv-permutation (zero-shuffle PV): bijective within each 32-block; swaps
// the g(2b)/e2(1b) bit-fields so QK^T output regs are directly PV A-fragment.
__device__ __forceinline__ int kv_sigma(int kv) {
    return (kv & ~31) | (((kv >> 2) & 3) << 3) | (((kv >> 4) & 1) << 2) |
           (kv & 3);
}

#define GLOAD16(gp, sp)                                                        \
    __builtin_amdgcn_global_load_lds(                                          \
        (const __attribute__((address_space(1))) void*)(gp),                   \
        (__attribute__((address_space(3))) void*)(sp), 16, 0, 0)

// ---------------------------------------------------------------------------
// LayerNorm over bf16 residual stream xb (+ fused residual add, 2 deltas).
// MODE 0: y = LN(xb)                         (xb unchanged)
// MODE 1: v = xb + d0 + d1 + dbias; xb = v;  y = LN(v)
// ---------------------------------------------------------------------------
template <int MODE>
__global__ __launch_bounds__(256) void ln_res(
    u16* __restrict__ xb, const u16* __restrict__ d0,
    const u16* __restrict__ d1, const float* __restrict__ dbias,
    const float* __restrict__ g, const float* __restrict__ b,
    u16* __restrict__ y) {
    int row = blockIdx.x;
    u16x4 xv = ((const u16x4*)(xb + (size_t)row * DIM_))[threadIdx.x];
    float4 v = {bf2f(xv[0]), bf2f(xv[1]), bf2f(xv[2]), bf2f(xv[3])};
    if constexpr (MODE == 1) {
        u16x4 a0 = ((const u16x4*)(d0 + (size_t)row * DIM_))[threadIdx.x];
        u16x4 a1 = ((const u16x4*)(d1 + (size_t)row * DIM_))[threadIdx.x];
        float4 bb4 = ((const float4*)dbias)[threadIdx.x];
        v.x += bf2f(a0[0]) + bf2f(a1[0]) + bb4.x;
        v.y += bf2f(a0[1]) + bf2f(a1[1]) + bb4.y;
        v.z += bf2f(a0[2]) + bf2f(a1[2]) + bb4.z;
        v.w += bf2f(a0[3]) + bf2f(a1[3]) + bb4.w;
        u16x4 xo = {f2bf(v.x), f2bf(v.y), f2bf(v.z), f2bf(v.w)};
        ((u16x4*)(xb + (size_t)row * DIM_))[threadIdx.x] = xo;
    }
    float s  = v.x + v.y + v.z + v.w;
    float ss = v.x * v.x + v.y * v.y + v.z * v.z + v.w * v.w;
    #pragma unroll
    for (int off = 32; off; off >>= 1) {
        s  += __shfl_down(s, off);
        ss += __shfl_down(ss, off);
    }
    __shared__ float red[10];
    int wid = threadIdx.x >> 6, lane = threadIdx.x & 63;
    if (lane == 0) { red[wid] = s; red[4 + wid] = ss; }
    __syncthreads();
    if (threadIdx.x == 0) {
        float ts  = red[0] + red[1] + red[2] + red[3];
        float tss = red[4] + red[5] + red[6] + red[7];
        float mu  = ts * (1.0f / DIM_);
        float var = tss * (1.0f / DIM_) - mu * mu;
        red[8] = mu;
        red[9] = rsqrtf(var + 1e-5f);
    }
    __syncthreads();
    float mu = red[8], rs = red[9];
    float4 gg = ((const float4*)g)[threadIdx.x];
    float4 bb = ((const float4*)b)[threadIdx.x];
    u16x4 o;
    o[0] = f2bf((v.x - mu) * rs * gg.x + bb.x);
    o[1] = f2bf((v.y - mu) * rs * gg.y + bb.y);
    o[2] = f2bf((v.z - mu) * rs * gg.z + bb.z);
    o[3] = f2bf((v.w - mu) * rs * gg.w + bb.w);
    ((u16x4*)(y + (size_t)row * DIM_))[threadIdx.x] = o;
}

// Final residual: xout(fp32) = xb + d0 + d1 + dbias
__global__ __launch_bounds__(256) void res_add(
    float* __restrict__ xout, const u16* __restrict__ xb,
    const u16* __restrict__ d0, const u16* __restrict__ d1,
    const float* __restrict__ dbias) {
    int row = blockIdx.x;
    u16x4 xv = ((const u16x4*)(xb + (size_t)row * DIM_))[threadIdx.x];
    u16x4 a0 = ((const u16x4*)(d0 + (size_t)row * DIM_))[threadIdx.x];
    u16x4 a1 = ((const u16x4*)(d1 + (size_t)row * DIM_))[threadIdx.x];
    float4 bb4 = ((const float4*)dbias)[threadIdx.x];
    float4 v;
    v.x = bf2f(xv[0]) + bf2f(a0[0]) + bf2f(a1[0]) + bb4.x;
    v.y = bf2f(xv[1]) + bf2f(a0[1]) + bf2f(a1[1]) + bb4.y;
    v.z = bf2f(xv[2]) + bf2f(a0[2]) + bf2f(a1[2]) + bb4.z;
    v.w = bf2f(xv[3]) + bf2f(a0[3]) + bf2f(a1[3]) + bb4.w;
    ((float4*)(xout + (size_t)row * DIM_))[threadIdx.x] = v;
}

// ---------------------------------------------------------------------------
// fp32 -> bf16 cast of two buffers in one dispatch (float4 per thread)
// ---------------------------------------------------------------------------
__global__ __launch_bounds__(256) void cast2_kernel(
    const float* __restrict__ in0, u16* __restrict__ out0, int n0,
    const float* __restrict__ in1, u16* __restrict__ out1) {
    int i = blockIdx.x * 256 + threadIdx.x;
    if (i < n0) {
        float4 v = ((const float4*)in0)[i];
        u16x4 o = {f2bf(v.x), f2bf(v.y), f2bf(v.z), f2bf(v.w)};
        ((u16x4*)out0)[i] = o;
    } else {
        int j = i - n0;
        float4 v = ((const float4*)in1)[j];
        u16x4 o = {f2bf(v.x), f2bf(v.y), f2bf(v.z), f2bf(v.w)};
        ((u16x4*)out1)[j] = o;
    }
}

// ---------------------------------------------------------------------------
// Fused weight prep for one layer: transpose+cast ALL 7 weight matrices
// ---------------------------------------------------------------------------
struct PrepArgs {
    const float* src[7];
    int K[7];
    int N[7];
    int dstOff[7];
    int tileCum[7];
};

__global__ __launch_bounds__(256) void prep_weights(PrepArgs a,
                                                    u16* __restrict__ wt) {
    __shared__ float tile[32][33];
    int bid = blockIdx.x;
    int wi = 0;
    while (bid >= a.tileCum[wi]) ++wi;
    int tbase = wi ? a.tileCum[wi - 1] : 0;
    int tid = bid - tbase;
    int Kd = a.K[wi], Nd = a.N[wi];
    int ntx = Nd >> 5;
    int bx = (tid % ntx) * 32;
    int by = (tid / ntx) * 32;
    const float* W = a.src[wi];
    u16* Wt = wt + a.dstOff[wi];

    int t = threadIdx.x;
    int kl = t >> 3, n4 = (t & 7) * 4;
    float4 v = *(const float4*)(W + (size_t)(by + kl) * Nd + bx + n4);
    tile[kl][n4 + 0] = v.x; tile[kl][n4 + 1] = v.y;
    tile[kl][n4 + 2] = v.z; tile[kl][n4 + 3] = v.w;
    __syncthreads();
    int nl = t >> 3, k4 = (t & 7) * 4;
    u16x4 o;
    #pragma unroll
    for (int j = 0; j < 4; ++j) o[j] = f2bf(tile[k4 + j][nl]);
    *(u16x4*)(Wt + (size_t)(bx + nl) * Kd + by + k4) = o;
}

// ---------------------------------------------------------------------------
// MFMA GEMM: 128x128 tile, BK=32, 4 waves 2x2, 3 LDS buffers, counted vmcnt,
// stage-after-barrier, T1 swizzle, T5 setprio, zero-conflict LDS swizzle.
// SPLITK==2 (EPI=0): chunk bz writes its own half at Cout + bz*Mdim*Ndim
// (two bf16 delta buffers combined by the next ln_res/res_add).
// EPI: 0 = bf16 out (split-aware); 1 = +bias+gelu bf16;
//      4 = QKV: Q cols *SCQ -> big; K cols -> big; V cols ONLY -> vt
// ---------------------------------------------------------------------------
template <int EPI, int SPLITK>
__global__ __launch_bounds__(256, 3) void gemm_mfma3(
    const u16* __restrict__ A, const u16* __restrict__ Bt,
    const float* __restrict__ bias, void* __restrict__ Cout,
    u16* __restrict__ vt, int Mdim, int Ndim, int Kdim, int nx, int ny) {
    __shared__ __align__(16) u16 As[3][128 * 32];
    __shared__ __align__(16) u16 Bs[3][128 * 32];
    const int t = threadIdx.x;
    const int lane = t & 63, w = t >> 6;
    const int c = lane & 15, g = lane >> 4;
    const int wy = w >> 1, wx = w & 1;

    const int nwg = gridDim.x;
    const int wid = (blockIdx.x & 7) * (nwg >> 3) + (blockIdx.x >> 3);
    const int bx = wid % nx;
    const int by = (wid / nx) % ny;
    const int bz = wid / (nx * ny);
    const int m0 = by * 128, n0 = bx * 128;

    f32x4 acc[4][4] = {};

    const int srow = w * 32 + (lane >> 2);
    const int scb  = (((lane & 3) ^ ((srow >> 1) & 3)) * 8);
    const u16* Ag = A + (size_t)(m0 + srow) * Kdim + scb;
    const u16* Bg = Bt + (size_t)(n0 + srow) * Kdim + scb;

    auto stage = [&](int buf, int k0) {
        GLOAD16(Ag + k0, &As[buf][w * 1024]);
        GLOAD16(Ag + k0 + (size_t)16 * Kdim, &As[buf][w * 1024 + 512]);
        GLOAD16(Bg + k0, &Bs[buf][w * 1024]);
        GLOAD16(Bg + k0 + (size_t)16 * Kdim, &Bs[buf][w * 1024 + 512]);
    };
    const int rsw = (c >> 1) & 3;
    auto compute = [&](int buf) {
        bf16x8 a[4], b[4];
        #pragma unroll
        for (int i = 0; i < 4; ++i)
            a[i] = *(const bf16x8*)&As[buf][(wy * 64 + i * 16 + c) * 32 +
                                            ((g ^ rsw) * 8)];
        #pragma unroll
        for (int j = 0; j < 4; ++j)
            b[j] = *(const bf16x8*)&Bs[buf][(wx * 64 + j * 16 + c) * 32 +
                                            ((g ^ rsw) * 8)];
        __builtin_amdgcn_s_setprio(1);
        #pragma unroll
        for (int i = 0; i < 4; ++i)
            #pragma unroll
            for (int j = 0; j < 4; ++j)
                acc[i][j] = __builtin_amdgcn_mfma_f32_16x16x32_bf16(
                    a[i], b[j], acc[i][j], 0, 0, 0);
        __builtin_amdgcn_s_setprio(0);
    };

    const int kchunk = Kdim / SPLITK;
    const int kbeg = bz * kchunk;
    const int nsteps = kchunk / 32;

    stage(0, kbeg);
    stage(1, kbeg + 32);
    int cb = 0, sb = 2;
    for (int s = 0; s < nsteps; ++s) {
        if (s + 1 < nsteps)
            asm volatile("s_waitcnt vmcnt(4)" ::: "memory");
        else
            asm volatile("s_waitcnt vmcnt(0)" ::: "memory");
        __builtin_amdgcn_s_barrier();
        if (s + 2 < nsteps) {
            stage(sb, kbeg + (s + 2) * 32);
            sb = (sb == 2) ? 0 : sb + 1;
        }
        compute(cb);
        cb = (cb == 2) ? 0 : cb + 1;
    }

    const size_t outOff = (SPLITK > 1) ? (size_t)bz * Mdim * Ndim : 0;

    #pragma unroll
    for (int i = 0; i < 4; ++i) {
        int row0 = m0 + wy * 64 + i * 16 + g * 4;
        #pragma unroll
        for (int j = 0; j < 4; ++j) {
            int col = n0 + wx * 64 + j * 16 + c;
            u16x4 o4;
            #pragma unroll
            for (int r = 0; r < 4; ++r) {
                float v = acc[i][j][r];
                size_t idx = (size_t)(row0 + r) * Ndim + col;
                if constexpr (EPI == 0) {
                    ((u16*)Cout)[outOff + idx] = f2bf(v);
                } else if constexpr (EPI == 4) {
                    if (col < 1024) {
                        ((u16*)Cout)[idx] = f2bf(v * SCQ);
                    } else if (col < 2048) {
                        ((u16*)Cout)[idx] = f2bf(v);
                    } else {
                        o4[r] = f2bf(v);  // V: only vt is written
                    }
                } else if constexpr (EPI == 1) {
                    v += bias[col];
                    ((u16*)Cout)[idx] = f2bf(gelu_fast(v));
                }
            }
            if constexpr (EPI == 4) {
                if (n0 + wx * 64 + j * 16 >= 2048) {
                    int hh = (col - 2048) >> 6;
                    int dd = col & 63;
                    int bi = row0 / 1024;
                    int kv = row0 % 1024;
                    int kvs = kv_sigma(kv);
                    *(u16x4*)&vt[(((size_t)bi * HEADS_ + hh) * 64 + dd) * 1024 +
                                 kvs] = o4;
                }
            }
        }
    }
}

// ---------------------------------------------------------------------------
// Dual GEMM: Wkv (1024 tiles) + Wq (256 tiles) on one 1280-block grid.
// K cols -> big; V cols ONLY -> vt (kv-permuted); Wq output scaled by SCQ.
// ---------------------------------------------------------------------------
__global__ __launch_bounds__(256, 3) void gemm_dual(
    const u16* __restrict__ Akv, const u16* __restrict__ Btkv,
    u16* __restrict__ Ckv, u16* __restrict__ vt,
    const u16* __restrict__ Aq, const u16* __restrict__ Btq,
    u16* __restrict__ Cq) {
    __shared__ __align__(16) u16 As[3][128 * 32];
    __shared__ __align__(16) u16 Bs[3][128 * 32];
    const int t = threadIdx.x;
    const int lane = t & 63, w = t >> 6;
    const int c = lane & 15, g = lane >> 4;
    const int wy = w >> 1, wx = w & 1;
    const int Kdim = 1024;

    const int nwg = gridDim.x;  // 1280
    const int wid = (blockIdx.x & 7) * (nwg >> 3) + (blockIdx.x >> 3);
    const bool pkv = wid < 1024;
    const u16* A;
    const u16* Bt;
    u16* Cc;
    int Ndim, bx, by;
    if (pkv) {
        A = Akv; Bt = Btkv; Cc = Ckv; Ndim = 2048;
        bx = wid & 15; by = wid >> 4;
    } else {
        int w2 = wid - 1024;
        A = Aq; Bt = Btq; Cc = Cq; Ndim = 1024;
        bx = w2 & 7; by = w2 >> 3;
    }
    const int m0 = by * 128, n0 = bx * 128;

    f32x4 acc[4][4] = {};

    const int srow = w * 32 + (lane >> 2);
    const int scb  = (((lane & 3) ^ ((srow >> 1) & 3)) * 8);
    const u16* Ag = A + (size_t)(m0 + srow) * Kdim + scb;
    const u16* Bg = Bt + (size_t)(n0 + srow) * Kdim + scb;

    auto stage = [&](int buf, int k0) {
        GLOAD16(Ag + k0, &As[buf][w * 1024]);
        GLOAD16(Ag + k0 + (size_t)16 * Kdim, &As[buf][w * 1024 + 512]);
        GLOAD16(Bg + k0, &Bs[buf][w * 1024]);
        GLOAD16(Bg + k0 + (size_t)16 * Kdim, &Bs[buf][w * 1024 + 512]);
    };
    const int rsw = (c >> 1) & 3;
    auto compute = [&](int buf) {
        bf16x8 a[4], b[4];
        #pragma unroll
        for (int i = 0; i < 4; ++i)
            a[i] = *(const bf16x8*)&As[buf][(wy * 64 + i * 16 + c) * 32 +
                                            ((g ^ rsw) * 8)];
        #pragma unroll
        for (int j = 0; j < 4; ++j)
            b[j] = *(const bf16x8*)&Bs[buf][(wx * 64 + j * 16 + c) * 32 +
                                            ((g ^ rsw) * 8)];
        __builtin_amdgcn_s_setprio(1);
        #pragma unroll
        for (int i = 0; i < 4; ++i)
            #pragma unroll
            for (int j = 0; j < 4; ++j)
                acc[i][j] = __builtin_amdgcn_mfma_f32_16x16x32_bf16(
                    a[i], b[j], acc[i][j], 0, 0, 0);
        __builtin_amdgcn_s_setprio(0);
    };

    stage(0, 0);
    stage(1, 32);
    int cb = 0, sb = 2;
    const int nsteps = 32;
    for (int s = 0; s < nsteps; ++s) {
        if (s + 1 < nsteps)
            asm volatile("s_waitcnt vmcnt(4)" ::: "memory");
        else
            asm volatile("s_waitcnt vmcnt(0)" ::: "memory");
        __builtin_amdgcn_s_barrier();
        if (s + 2 < nsteps) {
            stage(sb, (s + 2) * 32);
            sb = (sb == 2) ? 0 : sb + 1;
        }
        compute(cb);
        cb = (cb == 2) ? 0 : cb + 1;
    }

    #pragma unroll
    for (int i = 0; i < 4; ++i) {
        int row0 = m0 + wy * 64 + i * 16 + g * 4;
        #pragma unroll
        for (int j = 0; j < 4; ++j) {
            int col = n0 + wx * 64 + j * 16 + c;
            u16x4 o4;
            #pragma unroll
            for (int r = 0; r < 4; ++r) {
                float v = acc[i][j][r];
                size_t idx = (size_t)(row0 + r) * Ndim + col;
                if (pkv) {
                    u16 bv = f2bf(v);
                    if (col < 1024) Cc[idx] = bv;  // K only; V region dead
                    o4[r] = bv;
                } else {
                    Cc[idx] = f2bf(v * SCQ);
                }
            }
            if (pkv && (n0 + wx * 64 + j * 16 >= 1024)) {
                int hh = (col - 1024) >> 6;
                int dd = col & 63;
                int bi = row0 / 2048;
                int kv = row0 % 2048;
                int kvs = kv_sigma(kv);
                *(u16x4*)&vt[(((size_t)bi * HEADS_ + hh) * 64 + dd) * 2048 +
                             kvs] = o4;
            }
        }
    }
}

// ---------------------------------------------------------------------------
// MFMA flash attention v7 (R13-proven): TWO 64-row q-groups per block share
// each staged K/V tile; grid 512 blocks; 3-buffer counted-vmcnt pipeline;
// zero-shuffle PV + ones-column lr; v_max3 tree; defer-max; exp2-domain
// softmax; cvt_pk packing; XCD swizzle.
// ---------------------------------------------------------------------------
template <int KLEN, int IS_SA>
__global__ __launch_bounds__(256) void attn_mfma3(
    const u16* __restrict__ Qsrc, const u16* __restrict__ Ksrc,
    const u16* __restrict__ Vtg, const int* __restrict__ mask,
    u16* __restrict__ O) {
    constexpr int QSTR = IS_SA ? 3 * INNER_ : INNER_;
    constexpr int KSTR = IS_SA ? 3 * INNER_ : 2 * INNER_;
    constexpr int KOFF = IS_SA ? INNER_ : 0;

    __shared__ __align__(16) u16 Ks[3][64 * 64];
    __shared__ __align__(16) u16 Vs[3][64 * 64];

    const int t = threadIdx.x;
    const int lane = t & 63, w = t >> 6;
    const int c = lane & 15, g = lane >> 4;

    const int nwg = gridDim.x;  // 512
    const int wid = (blockIdx.x & 7) * (nwg >> 3) + (blockIdx.x >> 3);
    const int qb = wid & 7;
    const int h  = (wid >> 3) & 15;
    const int bb = wid >> 7;
    const int q0 = qb * 128;
    const int kvbase = bb * KLEN;

    const u16* qp0 =
        Qsrc + (size_t)(bb * N_ + q0 + w * 16 + c) * QSTR + h * 64 + g * 8;
    const u16* qp1 = qp0 + (size_t)64 * QSTR;
    bf16x8 qf0[2], qf1[2];
    qf0[0] = *(const bf16x8*)qp0;
    qf0[1] = *(const bf16x8*)(qp0 + 32);
    qf1[0] = *(const bf16x8*)qp1;
    qf1[1] = *(const bf16x8*)(qp1 + 32);

    const int sl_r = lane >> 3;
    const int scol = ((lane & 7) ^ sl_r) * 8;
    const int r0 = w * 16, r1 = w * 16 + 8;
    const u16* kp0 = Ksrc + (size_t)(kvbase + r0 + sl_r) * KSTR + KOFF +
                     h * 64 + scol;
    const u16* kp1 = Ksrc + (size_t)(kvbase + r1 + sl_r) * KSTR + KOFF +
                     h * 64 + scol;
    const u16* vp0 =
        Vtg + ((size_t)(bb * HEADS_ + h) * 64 + r0 + sl_r) * KLEN + scol;
    const u16* vp1 =
        Vtg + ((size_t)(bb * HEADS_ + h) * 64 + r1 + sl_r) * KLEN + scol;
    const int* mp = mask + bb * N_ + lane;

    auto stageKV = [&](int buf) {
        GLOAD16(kp0, &Ks[buf][r0 * 64]);
        GLOAD16(kp1, &Ks[buf][r1 * 64]);
        GLOAD16(vp0, &Vs[buf][r0 * 64]);
        GLOAD16(vp1, &Vs[buf][r1 * 64]);
        kp0 += (size_t)64 * KSTR;
        kp1 += (size_t)64 * KSTR;
        vp0 += 64;
        vp1 += 64;
    };

    f32x4 o0[4] = {}, o1[4] = {};
    f32x4 oL0 = {}, oL1 = {};
    float mr0 = -1e30f, mr1 = -1e30f;
    const i32x4 onesI = {0x3F803F80, 0x3F803F80, 0x3F803F80, 0x3F803F80};
    const bf16x8 ones = *(const bf16x8*)&onesI;
    constexpr int NT = KLEN / 64;

    stageKV(0);
    stageKV(1);
    int cb = 0, sb = 2;

    for (int kt = 0; kt < NT; ++kt) {
        if (kt + 1 < NT)
            asm volatile("s_waitcnt vmcnt(4)" ::: "memory");
        else
            asm volatile("s_waitcnt vmcnt(0)" ::: "memory");
        __builtin_amdgcn_s_barrier();
        int mbit = 1;
        if constexpr (IS_SA) {
            mbit = *mp;
            mp += 64;
        }
        if (kt + 2 < NT) {
            stageKV(sb);
            sb = (sb == 2) ? 0 : sb + 1;
        }

        // S^T = K Q^T for both q-groups; K fragment loaded once
        f32x4 sv0[4] = {}, sv1[4] = {};
        #pragma unroll
        for (int kvb = 0; kvb < 4; ++kvb) {
            #pragma unroll
            for (int f = 0; f < 2; ++f) {
                bf16x8 kf = *(const bf16x8*)&Ks[cb][(kvb * 16 + c) * 64 +
                                                    (((g + 4 * f) ^ (c & 7)) * 8)];
                sv0[kvb] = __builtin_amdgcn_mfma_f32_16x16x32_bf16(
                    kf, qf0[f], sv0[kvb], 0, 0, 0);
                sv1[kvb] = __builtin_amdgcn_mfma_f32_16x16x32_bf16(
                    kf, qf1[f], sv1[kvb], 0, 0, 0);
            }
        }

        if constexpr (IS_SA) {
            unsigned long long ball = __ballot(mbit != 0);
            if (ball != ~0ull) {
                float negm_reg = mbit ? 0.f : 2.0e10f;
                #pragma unroll
                for (int kvb = 0; kvb < 4; ++kvb)
                    #pragma unroll
                    for (int r = 0; r < 4; ++r) {
                        float nm = __shfl(negm_reg, kvb * 16 + g * 4 + r);
                        sv0[kvb][r] -= nm;
                        sv1[kvb][r] -= nm;
                    }
            }
        }

        // local max per group (max3 tree)
        float a0 = max3f(sv0[0][0], sv0[0][1], sv0[0][2]);
        float a1 = max3f(sv0[0][3], sv0[1][0], sv0[1][1]);
        float a2 = max3f(sv0[1][2], sv0[1][3], sv0[2][0]);
        float a3 = max3f(sv0[2][1], sv0[2][2], sv0[2][3]);
        float a4 = max3f(sv0[3][0], sv0[3][1], sv0[3][2]);
        float tm0 = fmaxf(max3f(a0, a1, a2), max3f(a3, a4, sv0[3][3]));
        float b0 = max3f(sv1[0][0], sv1[0][1], sv1[0][2]);
        float b1 = max3f(sv1[0][3], sv1[1][0], sv1[1][1]);
        float b2 = max3f(sv1[1][2], sv1[1][3], sv1[2][0]);
        float b3 = max3f(sv1[2][1], sv1[2][2], sv1[2][3]);
        float b4 = max3f(sv1[3][0], sv1[3][1], sv1[3][2]);
        float tm1 = fmaxf(max3f(b0, b1, b2), max3f(b3, b4, sv1[3][3]));

        if (!__all(fmaxf(tm0 - mr0, tm1 - mr1) <= 8.0f)) {  // rare rescale
            float t0 = fmaxf(tm0, __shfl_xor(tm0, 16));
            t0 = fmaxf(t0, __shfl_xor(t0, 32));
            float t1 = fmaxf(tm1, __shfl_xor(tm1, 16));
            t1 = fmaxf(t1, __shfl_xor(t1, 32));
            float mn0 = fmaxf(mr0, t0), mn1 = fmaxf(mr1, t1);
            float c0 = exp2_fast(mr0 - mn0), c1 = exp2_fast(mr1 - mn1);
            mr0 = mn0; mr1 = mn1;
            float c0O[4], c1O[4];
            #pragma unroll
            for (int r = 0; r < 4; ++r) {
                c0O[r] = __shfl(c0, g * 4 + r);
                c1O[r] = __shfl(c1, g * 4 + r);
            }
            #pragma unroll
            for (int db = 0; db < 4; ++db)
                #pragma unroll
                for (int r = 0; r < 4; ++r) {
                    o0[db][r] *= c0O[r];
                    o1[db][r] *= c1O[r];
                }
            #pragma unroll
            for (int r = 0; r < 4; ++r) {
                oL0[r] *= c0O[r];
                oL1[r] *= c1O[r];
            }
        }

        #pragma unroll
        for (int kvb = 0; kvb < 4; ++kvb)
            #pragma unroll
            for (int r = 0; r < 4; ++r) {
                sv0[kvb][r] = exp2_fast(sv0[kvb][r] - mr0);
                sv1[kvb][r] = exp2_fast(sv1[kvb][r] - mr1);
            }

        unsigned pk0[4][2], pk1[4][2];
        #pragma unroll
        for (int kvb = 0; kvb < 4; ++kvb)
            #pragma unroll
            for (int j = 0; j < 2; ++j) {
                pk0[kvb][j] = cvt_pk_bf16(sv0[kvb][2 * j], sv0[kvb][2 * j + 1]);
                pk1[kvb][j] = cvt_pk_bf16(sv1[kvb][2 * j], sv1[kvb][2 * j + 1]);
            }

        // zero-shuffle PV + ones-column row-sum; V fragment loaded once
        #pragma unroll
        for (int pv = 0; pv < 2; ++pv) {
            i32x4 tw0 = {(int)pk0[2 * pv][0], (int)pk0[2 * pv][1],
                         (int)pk0[2 * pv + 1][0], (int)pk0[2 * pv + 1][1]};
            i32x4 tw1 = {(int)pk1[2 * pv][0], (int)pk1[2 * pv][1],
                         (int)pk1[2 * pv + 1][0], (int)pk1[2 * pv + 1][1]};
            bf16x8 pa0 = *(bf16x8*)&tw0;
            bf16x8 pa1 = *(bf16x8*)&tw1;
            oL0 = __builtin_amdgcn_mfma_f32_16x16x32_bf16(pa0, ones, oL0, 0, 0, 0);
            oL1 = __builtin_amdgcn_mfma_f32_16x16x32_bf16(pa1, ones, oL1, 0, 0, 0);
            #pragma unroll
            for (int db = 0; db < 4; ++db) {
                bf16x8 vf = *(const bf16x8*)&Vs[cb][(db * 16 + c) * 64 +
                                                    (((g + 4 * pv) ^ (c & 7)) * 8)];
                o0[db] = __builtin_amdgcn_mfma_f32_16x16x32_bf16(pa0, vf,
                                                                 o0[db], 0, 0, 0);
                o1[db] = __builtin_amdgcn_mfma_f32_16x16x32_bf16(pa1, vf,
                                                                 o1[db], 0, 0, 0);
            }
        }
        cb = (cb == 2) ? 0 : cb + 1;
    }

    float i0[4], i1[4];
    #pragma unroll
    for (int r = 0; r < 4; ++r) {
        i0[r] = rcp_fast(oL0[r]);
        i1[r] = rcp_fast(oL1[r]);
    }
    #pragma unroll
    for (int db = 0; db < 4; ++db)
        #pragma unroll
        for (int r = 0; r < 4; ++r) {
            size_t idx =
                (size_t)(bb * N_ + q0 + w * 16 + g * 4 + r) * INNER_ +
                h * 64 + db * 16 + c;
            O[idx] = f2bf(o0[db][r] * i0[r]);
            O[idx + (size_t)64 * INNER_] = f2bf(o1[db][r] * i1[r]);
        }
}

// ---------------------------------------------------------------------------
extern "C" void kernel_launch(void* const* d_in, const int* in_sizes, int n_in,
                              void* d_out, int out_size, void* d_ws,
                              size_t ws_size, hipStream_t stream) {
    const float* x     = (const float*)d_in[0];
    const float* ctx   = (const float*)d_in[1];
    const int*   mask  = (const int*)d_in[2];
    const float* ln_g  = (const float*)d_in[3];
    const float* ln_b  = (const float*)d_in[4];
    const float* Wqkv  = (const float*)d_in[5];
    const float* Wo_sa = (const float*)d_in[6];
    const float* bo_sa = (const float*)d_in[7];
    const float* Wkv   = (const float*)d_in[8];
    const float* Wq    = (const float*)d_in[9];
    const float* Wo_ca = (const float*)d_in[10];
    const float* bo_ca = (const float*)d_in[11];
    const float* W1    = (const float*)d_in[12];
    const float* b1    = (const float*)d_in[13];
    const float* W2    = (const float*)d_in[14];
    const float* b2    = (const float*)d_in[15];
    float* xout = (float*)d_out;

    char* ws = (char*)d_ws;
    u16* lnout = (u16*)ws;                        // 8MB (also attn out)
    u16* big   = (u16*)(ws + (8ull << 20));       // 32MB: qkv / kv / h1
    u16* qca   = (u16*)(ws + (40ull << 20));      // 8MB
    u16* ctxb  = (u16*)(ws + (48ull << 20));      // 16MB
    u16* wt    = (u16*)(ws + (64ull << 20));      // 32MB: transposed wts
    u16* xb    = (u16*)(ws + (96ull << 20));      // 8MB: bf16 residual stream
    u16* R1    = (u16*)(ws + (104ull << 20));     // 16MB: vt | d0+d1
    u16* aout  = lnout;

    // wt sub-offsets (elements)
    const int O_QKV = 0;
    const int O_WOSA = 3145728;
    const int O_WQ   = 4194304;
    const int O_WKV  = 5242880;
    const int O_WOCA = 7340032;
    const int O_W1   = 8388608;
    const int O_W2   = 12582912;

    const int ROWS = B_ * N_;    // 4096
    const int HALF = ROWS * DIM_;
    dim3 blk(256);

    // one dispatch casts both ctx (8M f32) and x (4M f32)
    cast2_kernel<<<(B_ * M_ * CTX_ + B_ * N_ * DIM_) / 1024, blk, 0, stream>>>(
        ctx, ctxb, B_ * M_ * CTX_ / 4, x, xb);

    for (int i = 0; i < DEPTH_; ++i) {
        const float* g  = ln_g + (size_t)(i * 3) * DIM_;
        const float* bb = ln_b + (size_t)(i * 3) * DIM_;

        PrepArgs pa;
        pa.src[0] = Wqkv  + (size_t)i * DIM_ * 3 * INNER_;
        pa.src[1] = Wo_sa + (size_t)i * INNER_ * DIM_;
        pa.src[2] = Wq    + (size_t)i * DIM_ * INNER_;
        pa.src[3] = Wkv   + (size_t)i * CTX_ * 2 * INNER_;
        pa.src[4] = Wo_ca + (size_t)i * INNER_ * DIM_;
        pa.src[5] = W1    + (size_t)i * DIM_ * MLP_;
        pa.src[6] = W2    + (size_t)i * MLP_ * DIM_;
        int Ks_[7] = {1024, 1024, 1024, 1024, 1024, 1024, 4096};
        int Ns_[7] = {3072, 1024, 1024, 2048, 1024, 4096, 1024};
        int Of_[7] = {O_QKV, O_WOSA, O_WQ, O_WKV, O_WOCA, O_W1, O_W2};
        int cum = 0;
        for (int k = 0; k < 7; ++k) {
            pa.K[k] = Ks_[k]; pa.N[k] = Ns_[k]; pa.dstOff[k] = Of_[k];
            cum += (Ks_[k] / 32) * (Ns_[k] / 32);
            pa.tileCum[k] = cum;
        }
        prep_weights<<<cum, blk, 0, stream>>>(pa, wt);

        // ---- self-attention ----
        if (i == 0)
            ln_res<0><<<ROWS, blk, 0, stream>>>(xb, nullptr, nullptr,
                                                nullptr, g, bb, lnout);
        else
            ln_res<1><<<ROWS, blk, 0, stream>>>(xb, R1, R1 + HALF,
                                                b2 + (size_t)(i - 1) * DIM_,
                                                g, bb, lnout);
        gemm_mfma3<4, 1><<<24 * 32, blk, 0, stream>>>(
            lnout, wt + O_QKV, nullptr, big, R1, ROWS, 3 * INNER_, DIM_,
            24, 32);
        attn_mfma3<N_, 1><<<512, blk, 0, stream>>>(big, big, R1, mask, aout);
        gemm_mfma3<0, 2><<<8 * 32 * 2, blk, 0, stream>>>(
            aout, wt + O_WOSA, nullptr, R1, nullptr, ROWS, DIM_, INNER_,
            8, 32);

        // ---- cross-attention ----
        ln_res<1><<<ROWS, blk, 0, stream>>>(xb, R1, R1 + HALF,
                                            bo_sa + (size_t)i * DIM_,
                                            g + DIM_, bb + DIM_, lnout);
        gemm_dual<<<1280, blk, 0, stream>>>(ctxb, wt + O_WKV, big, R1,
                                            lnout, wt + O_WQ, qca);
        attn_mfma3<M_, 0><<<512, blk, 0, stream>>>(qca, big, R1, mask, aout);
        gemm_mfma3<0, 2><<<8 * 32 * 2, blk, 0, stream>>>(
            aout, wt + O_WOCA, nullptr, R1, nullptr, ROWS, DIM_, INNER_,
            8, 32);

        // ---- feed-forward ----
        ln_res<1><<<ROWS, blk, 0, stream>>>(xb, R1, R1 + HALF,
                                            bo_ca + (size_t)i * DIM_,
                                            g + 2 * DIM_, bb + 2 * DIM_,
                                            lnout);
        gemm_mfma3<1, 1><<<32 * 32, blk, 0, stream>>>(
            lnout, wt + O_W1, b1 + (size_t)i * MLP_, big, nullptr, ROWS, MLP_,
            DIM_, 32, 32);
        gemm_mfma3<0, 2><<<8 * 32 * 2, blk, 0, stream>>>(
            big, wt + O_W2, nullptr, R1, nullptr, ROWS, DIM_, MLP_, 8, 32);
    }
    res_add<<<ROWS, blk, 0, stream>>>(xout, xb, R1, R1 + HALF,
                                      b2 + (size_t)(DEPTH_ - 1) * DIM_);
}

// Round 17
// 1455.450 us; speedup vs baseline: 1.0547x; 1.0075x over previous
//
#include <hip/hip_runtime.h>
#include <math.h>

#define DEPTH_ 4
#define DIM_ 1024
#define HEADS_ 16
#define DHEAD_ 64
#define MLP_ 4096
#define CTX_ 1024
#define INNER_ 1024
#define B_ 4
#define N_ 1024
#define M_ 2048

typedef unsigned short u16;
typedef __attribute__((ext_vector_type(4))) unsigned short u16x4;
typedef __attribute__((ext_vector_type(8))) short bf16x8;
typedef __attribute__((ext_vector_type(4))) float f32x4;
typedef __attribute__((ext_vector_type(4))) int i32x4;

// Q pre-scale: 1/sqrt(64) * log2(e)  (softmax runs in exp2 domain)
#define SCQ 0.18033688011112042f

__device__ __forceinline__ u16 f2bf(float f) {
    unsigned u = __float_as_uint(f);
    return (u16)((u + 0x7fffu + ((u >> 16) & 1u)) >> 16);
}

__device__ __forceinline__ float bf2f(u16 v) {
    return __uint_as_float(((unsigned)v) << 16);
}

__device__ __forceinline__ float exp2_fast(float x) {
    float r;
    asm("v_exp_f32 %0, %1" : "=v"(r) : "v"(x));
    return r;
}

__device__ __forceinline__ float rcp_fast(float x) {
    float r;
    asm("v_rcp_f32 %0, %1" : "=v"(r) : "v"(x));
    return r;
}

__device__ __forceinline__ float max3f(float a, float b, float c) {
    float r;
    asm("v_max3_f32 %0, %1, %2, %3" : "=v"(r) : "v"(a), "v"(b), "v"(c));
    return r;
}

__device__ __forceinline__ unsigned cvt_pk_bf16(float lo, float hi) {
    unsigned r;
    asm("v_cvt_pk_bf16_f32 %0, %1, %2" : "=v"(r) : "v"(lo), "v"(hi));
    return r;
}

// gelu(x) = x * sigmoid(2*0.7978845608*(x + 0.044715 x^3)), exp2 domain
__device__ __forceinline__ float gelu_fast(float v) {
    float t = v + 0.044715f * v * v * v;
    float e = exp2_fast(-2.302221673f * t);
    return v * rcp_fast(1.0f + e);
}

// V^T kv-permutation (zero-shuffle PV): bijective within each 32-block; swaps
// the g(2b)/e2(1b) bit-fields so QK^T output regs are directly PV A-fragment.
__device__ __forceinline__ int kv_sigma(int kv) {
    return (kv & ~31) | (((kv >> 2) & 3) << 3) | (((kv >> 4) & 1) << 2) |
           (kv & 3);
}

#define GLOAD16(gp, sp)                                                        \
    __builtin_amdgcn_global_load_lds(                                          \
        (const __attribute__((address_space(1))) void*)(gp),                   \
        (__attribute__((address_space(3))) void*)(sp), 16, 0, 0)

// ---------------------------------------------------------------------------
// LayerNorm over bf16 residual stream xb (+ fused residual add, 2 deltas).
// MODE 0: y = LN(xb)                         (xb unchanged)
// MODE 1: v = xb + d0 + d1 + dbias; xb = v;  y = LN(v)
// ---------------------------------------------------------------------------
template <int MODE>
__global__ __launch_bounds__(256) void ln_res(
    u16* __restrict__ xb, const u16* __restrict__ d0,
    const u16* __restrict__ d1, const float* __restrict__ dbias,
    const float* __restrict__ g, const float* __restrict__ b,
    u16* __restrict__ y) {
    int row = blockIdx.x;
    u16x4 xv = ((const u16x4*)(xb + (size_t)row * DIM_))[threadIdx.x];
    float4 v = {bf2f(xv[0]), bf2f(xv[1]), bf2f(xv[2]), bf2f(xv[3])};
    if constexpr (MODE == 1) {
        u16x4 a0 = ((const u16x4*)(d0 + (size_t)row * DIM_))[threadIdx.x];
        u16x4 a1 = ((const u16x4*)(d1 + (size_t)row * DIM_))[threadIdx.x];
        float4 bb4 = ((const float4*)dbias)[threadIdx.x];
        v.x += bf2f(a0[0]) + bf2f(a1[0]) + bb4.x;
        v.y += bf2f(a0[1]) + bf2f(a1[1]) + bb4.y;
        v.z += bf2f(a0[2]) + bf2f(a1[2]) + bb4.z;
        v.w += bf2f(a0[3]) + bf2f(a1[3]) + bb4.w;
        u16x4 xo = {f2bf(v.x), f2bf(v.y), f2bf(v.z), f2bf(v.w)};
        ((u16x4*)(xb + (size_t)row * DIM_))[threadIdx.x] = xo;
    }
    float s  = v.x + v.y + v.z + v.w;
    float ss = v.x * v.x + v.y * v.y + v.z * v.z + v.w * v.w;
    #pragma unroll
    for (int off = 32; off; off >>= 1) {
        s  += __shfl_down(s, off);
        ss += __shfl_down(ss, off);
    }
    __shared__ float red[10];
    int wid = threadIdx.x >> 6, lane = threadIdx.x & 63;
    if (lane == 0) { red[wid] = s; red[4 + wid] = ss; }
    __syncthreads();
    if (threadIdx.x == 0) {
        float ts  = red[0] + red[1] + red[2] + red[3];
        float tss = red[4] + red[5] + red[6] + red[7];
        float mu  = ts * (1.0f / DIM_);
        float var = tss * (1.0f / DIM_) - mu * mu;
        red[8] = mu;
        red[9] = rsqrtf(var + 1e-5f);
    }
    __syncthreads();
    float mu = red[8], rs = red[9];
    float4 gg = ((const float4*)g)[threadIdx.x];
    float4 bb = ((const float4*)b)[threadIdx.x];
    u16x4 o;
    o[0] = f2bf((v.x - mu) * rs * gg.x + bb.x);
    o[1] = f2bf((v.y - mu) * rs * gg.y + bb.y);
    o[2] = f2bf((v.z - mu) * rs * gg.z + bb.z);
    o[3] = f2bf((v.w - mu) * rs * gg.w + bb.w);
    ((u16x4*)(y + (size_t)row * DIM_))[threadIdx.x] = o;
}

// Final residual: xout(fp32) = xb + d0 + d1 + dbias
__global__ __launch_bounds__(256) void res_add(
    float* __restrict__ xout, const u16* __restrict__ xb,
    const u16* __restrict__ d0, const u16* __restrict__ d1,
    const float* __restrict__ dbias) {
    int row = blockIdx.x;
    u16x4 xv = ((const u16x4*)(xb + (size_t)row * DIM_))[threadIdx.x];
    u16x4 a0 = ((const u16x4*)(d0 + (size_t)row * DIM_))[threadIdx.x];
    u16x4 a1 = ((const u16x4*)(d1 + (size_t)row * DIM_))[threadIdx.x];
    float4 bb4 = ((const float4*)dbias)[threadIdx.x];
    float4 v;
    v.x = bf2f(xv[0]) + bf2f(a0[0]) + bf2f(a1[0]) + bb4.x;
    v.y = bf2f(xv[1]) + bf2f(a0[1]) + bf2f(a1[1]) + bb4.y;
    v.z = bf2f(xv[2]) + bf2f(a0[2]) + bf2f(a1[2]) + bb4.z;
    v.w = bf2f(xv[3]) + bf2f(a0[3]) + bf2f(a1[3]) + bb4.w;
    ((float4*)(xout + (size_t)row * DIM_))[threadIdx.x] = v;
}

// ---------------------------------------------------------------------------
// fp32 -> bf16 cast of two buffers in one dispatch (float4 per thread)
// ---------------------------------------------------------------------------
__global__ __launch_bounds__(256) void cast2_kernel(
    const float* __restrict__ in0, u16* __restrict__ out0, int n0,
    const float* __restrict__ in1, u16* __restrict__ out1) {
    int i = blockIdx.x * 256 + threadIdx.x;
    if (i < n0) {
        float4 v = ((const float4*)in0)[i];
        u16x4 o = {f2bf(v.x), f2bf(v.y), f2bf(v.z), f2bf(v.w)};
        ((u16x4*)out0)[i] = o;
    } else {
        int j = i - n0;
        float4 v = ((const float4*)in1)[j];
        u16x4 o = {f2bf(v.x), f2bf(v.y), f2bf(v.z), f2bf(v.w)};
        ((u16x4*)out1)[j] = o;
    }
}

// ---------------------------------------------------------------------------
// Fused weight prep for one layer: transpose+cast ALL 7 weight matrices
// ---------------------------------------------------------------------------
struct PrepArgs {
    const float* src[7];
    int K[7];
    int N[7];
    int dstOff[7];
    int tileCum[7];
};

__global__ __launch_bounds__(256) void prep_weights(PrepArgs a,
                                                    u16* __restrict__ wt) {
    __shared__ float tile[32][33];
    int bid = blockIdx.x;
    int wi = 0;
    while (bid >= a.tileCum[wi]) ++wi;
    int tbase = wi ? a.tileCum[wi - 1] : 0;
    int tid = bid - tbase;
    int Kd = a.K[wi], Nd = a.N[wi];
    int ntx = Nd >> 5;
    int bx = (tid % ntx) * 32;
    int by = (tid / ntx) * 32;
    const float* W = a.src[wi];
    u16* Wt = wt + a.dstOff[wi];

    int t = threadIdx.x;
    int kl = t >> 3, n4 = (t & 7) * 4;
    float4 v = *(const float4*)(W + (size_t)(by + kl) * Nd + bx + n4);
    tile[kl][n4 + 0] = v.x; tile[kl][n4 + 1] = v.y;
    tile[kl][n4 + 2] = v.z; tile[kl][n4 + 3] = v.w;
    __syncthreads();
    int nl = t >> 3, k4 = (t & 7) * 4;
    u16x4 o;
    #pragma unroll
    for (int j = 0; j < 4; ++j) o[j] = f2bf(tile[k4 + j][nl]);
    *(u16x4*)(Wt + (size_t)(bx + nl) * Kd + by + k4) = o;
}

// ---------------------------------------------------------------------------
// MFMA GEMM: 128x128 tile, BK=32, 4 waves 2x2, 3 LDS buffers, counted vmcnt,
// stage-after-barrier, T1 swizzle, T5 setprio, zero-conflict LDS swizzle.
// SPLITK==2 (EPI=0): chunk bz writes its own half at Cout + bz*Mdim*Ndim
// (two bf16 delta buffers combined by the next ln_res/res_add).
// EPI: 0 = bf16 out (split-aware); 1 = +bias+gelu bf16;
//      4 = QKV: Q cols *SCQ -> big; K cols -> big; V cols ONLY -> vt
// ---------------------------------------------------------------------------
template <int EPI, int SPLITK>
__global__ __launch_bounds__(256, 3) void gemm_mfma3(
    const u16* __restrict__ A, const u16* __restrict__ Bt,
    const float* __restrict__ bias, void* __restrict__ Cout,
    u16* __restrict__ vt, int Mdim, int Ndim, int Kdim, int nx, int ny) {
    __shared__ __align__(16) u16 As[3][128 * 32];
    __shared__ __align__(16) u16 Bs[3][128 * 32];
    const int t = threadIdx.x;
    const int lane = t & 63, w = t >> 6;
    const int c = lane & 15, g = lane >> 4;
    const int wy = w >> 1, wx = w & 1;

    const int nwg = gridDim.x;
    const int wid = (blockIdx.x & 7) * (nwg >> 3) + (blockIdx.x >> 3);
    const int bx = wid % nx;
    const int by = (wid / nx) % ny;
    const int bz = wid / (nx * ny);
    const int m0 = by * 128, n0 = bx * 128;

    f32x4 acc[4][4] = {};

    const int srow = w * 32 + (lane >> 2);
    const int scb  = (((lane & 3) ^ ((srow >> 1) & 3)) * 8);
    const u16* Ag = A + (size_t)(m0 + srow) * Kdim + scb;
    const u16* Bg = Bt + (size_t)(n0 + srow) * Kdim + scb;

    auto stage = [&](int buf, int k0) {
        GLOAD16(Ag + k0, &As[buf][w * 1024]);
        GLOAD16(Ag + k0 + (size_t)16 * Kdim, &As[buf][w * 1024 + 512]);
        GLOAD16(Bg + k0, &Bs[buf][w * 1024]);
        GLOAD16(Bg + k0 + (size_t)16 * Kdim, &Bs[buf][w * 1024 + 512]);
    };
    const int rsw = (c >> 1) & 3;
    auto compute = [&](int buf) {
        bf16x8 a[4], b[4];
        #pragma unroll
        for (int i = 0; i < 4; ++i)
            a[i] = *(const bf16x8*)&As[buf][(wy * 64 + i * 16 + c) * 32 +
                                            ((g ^ rsw) * 8)];
        #pragma unroll
        for (int j = 0; j < 4; ++j)
            b[j] = *(const bf16x8*)&Bs[buf][(wx * 64 + j * 16 + c) * 32 +
                                            ((g ^ rsw) * 8)];
        __builtin_amdgcn_s_setprio(1);
        #pragma unroll
        for (int i = 0; i < 4; ++i)
            #pragma unroll
            for (int j = 0; j < 4; ++j)
                acc[i][j] = __builtin_amdgcn_mfma_f32_16x16x32_bf16(
                    a[i], b[j], acc[i][j], 0, 0, 0);
        __builtin_amdgcn_s_setprio(0);
    };

    const int kchunk = Kdim / SPLITK;
    const int kbeg = bz * kchunk;
    const int nsteps = kchunk / 32;

    stage(0, kbeg);
    stage(1, kbeg + 32);
    int cb = 0, sb = 2;
    for (int s = 0; s < nsteps; ++s) {
        if (s + 1 < nsteps)
            asm volatile("s_waitcnt vmcnt(4)" ::: "memory");
        else
            asm volatile("s_waitcnt vmcnt(0)" ::: "memory");
        __builtin_amdgcn_s_barrier();
        if (s + 2 < nsteps) {
            stage(sb, kbeg + (s + 2) * 32);
            sb = (sb == 2) ? 0 : sb + 1;
        }
        compute(cb);
        cb = (cb == 2) ? 0 : cb + 1;
    }

    const size_t outOff = (SPLITK > 1) ? (size_t)bz * Mdim * Ndim : 0;

    #pragma unroll
    for (int i = 0; i < 4; ++i) {
        int row0 = m0 + wy * 64 + i * 16 + g * 4;
        #pragma unroll
        for (int j = 0; j < 4; ++j) {
            int col = n0 + wx * 64 + j * 16 + c;
            u16x4 o4;
            #pragma unroll
            for (int r = 0; r < 4; ++r) {
                float v = acc[i][j][r];
                size_t idx = (size_t)(row0 + r) * Ndim + col;
                if constexpr (EPI == 0) {
                    ((u16*)Cout)[outOff + idx] = f2bf(v);
                } else if constexpr (EPI == 4) {
                    if (col < 1024) {
                        ((u16*)Cout)[idx] = f2bf(v * SCQ);
                    } else if (col < 2048) {
                        ((u16*)Cout)[idx] = f2bf(v);
                    } else {
                        o4[r] = f2bf(v);  // V: only vt is written
                    }
                } else if constexpr (EPI == 1) {
                    v += bias[col];
                    ((u16*)Cout)[idx] = f2bf(gelu_fast(v));
                }
            }
            if constexpr (EPI == 4) {
                if (n0 + wx * 64 + j * 16 >= 2048) {
                    int hh = (col - 2048) >> 6;
                    int dd = col & 63;
                    int bi = row0 / 1024;
                    int kv = row0 % 1024;
                    int kvs = kv_sigma(kv);
                    *(u16x4*)&vt[(((size_t)bi * HEADS_ + hh) * 64 + dd) * 1024 +
                                 kvs] = o4;
                }
            }
        }
    }
}

// ---------------------------------------------------------------------------
// Dual GEMM: Wkv (1024 tiles) + Wq (256 tiles) on one 1280-block grid.
// K cols -> big; V cols ONLY -> vt (kv-permuted); Wq output scaled by SCQ.
// ---------------------------------------------------------------------------
__global__ __launch_bounds__(256, 3) void gemm_dual(
    const u16* __restrict__ Akv, const u16* __restrict__ Btkv,
    u16* __restrict__ Ckv, u16* __restrict__ vt,
    const u16* __restrict__ Aq, const u16* __restrict__ Btq,
    u16* __restrict__ Cq) {
    __shared__ __align__(16) u16 As[3][128 * 32];
    __shared__ __align__(16) u16 Bs[3][128 * 32];
    const int t = threadIdx.x;
    const int lane = t & 63, w = t >> 6;
    const int c = lane & 15, g = lane >> 4;
    const int wy = w >> 1, wx = w & 1;
    const int Kdim = 1024;

    const int nwg = gridDim.x;  // 1280
    const int wid = (blockIdx.x & 7) * (nwg >> 3) + (blockIdx.x >> 3);
    const bool pkv = wid < 1024;
    const u16* A;
    const u16* Bt;
    u16* Cc;
    int Ndim, bx, by;
    if (pkv) {
        A = Akv; Bt = Btkv; Cc = Ckv; Ndim = 2048;
        bx = wid & 15; by = wid >> 4;
    } else {
        int w2 = wid - 1024;
        A = Aq; Bt = Btq; Cc = Cq; Ndim = 1024;
        bx = w2 & 7; by = w2 >> 3;
    }
    const int m0 = by * 128, n0 = bx * 128;

    f32x4 acc[4][4] = {};

    const int srow = w * 32 + (lane >> 2);
    const int scb  = (((lane & 3) ^ ((srow >> 1) & 3)) * 8);
    const u16* Ag = A + (size_t)(m0 + srow) * Kdim + scb;
    const u16* Bg = Bt + (size_t)(n0 + srow) * Kdim + scb;

    auto stage = [&](int buf, int k0) {
        GLOAD16(Ag + k0, &As[buf][w * 1024]);
        GLOAD16(Ag + k0 + (size_t)16 * Kdim, &As[buf][w * 1024 + 512]);
        GLOAD16(Bg + k0, &Bs[buf][w * 1024]);
        GLOAD16(Bg + k0 + (size_t)16 * Kdim, &Bs[buf][w * 1024 + 512]);
    };
    const int rsw = (c >> 1) & 3;
    auto compute = [&](int buf) {
        bf16x8 a[4], b[4];
        #pragma unroll
        for (int i = 0; i < 4; ++i)
            a[i] = *(const bf16x8*)&As[buf][(wy * 64 + i * 16 + c) * 32 +
                                            ((g ^ rsw) * 8)];
        #pragma unroll
        for (int j = 0; j < 4; ++j)
            b[j] = *(const bf16x8*)&Bs[buf][(wx * 64 + j * 16 + c) * 32 +
                                            ((g ^ rsw) * 8)];
        __builtin_amdgcn_s_setprio(1);
        #pragma unroll
        for (int i = 0; i < 4; ++i)
            #pragma unroll
            for (int j = 0; j < 4; ++j)
                acc[i][j] = __builtin_amdgcn_mfma_f32_16x16x32_bf16(
                    a[i], b[j], acc[i][j], 0, 0, 0);
        __builtin_amdgcn_s_setprio(0);
    };

    stage(0, 0);
    stage(1, 32);
    int cb = 0, sb = 2;
    const int nsteps = 32;
    for (int s = 0; s < nsteps; ++s) {
        if (s + 1 < nsteps)
            asm volatile("s_waitcnt vmcnt(4)" ::: "memory");
        else
            asm volatile("s_waitcnt vmcnt(0)" ::: "memory");
        __builtin_amdgcn_s_barrier();
        if (s + 2 < nsteps) {
            stage(sb, (s + 2) * 32);
            sb = (sb == 2) ? 0 : sb + 1;
        }
        compute(cb);
        cb = (cb == 2) ? 0 : cb + 1;
    }

    #pragma unroll
    for (int i = 0; i < 4; ++i) {
        int row0 = m0 + wy * 64 + i * 16 + g * 4;
        #pragma unroll
        for (int j = 0; j < 4; ++j) {
            int col = n0 + wx * 64 + j * 16 + c;
            u16x4 o4;
            #pragma unroll
            for (int r = 0; r < 4; ++r) {
                float v = acc[i][j][r];
                size_t idx = (size_t)(row0 + r) * Ndim + col;
                if (pkv) {
                    u16 bv = f2bf(v);
                    if (col < 1024) Cc[idx] = bv;  // K only; V region dead
                    o4[r] = bv;
                } else {
                    Cc[idx] = f2bf(v * SCQ);
                }
            }
            if (pkv && (n0 + wx * 64 + j * 16 >= 1024)) {
                int hh = (col - 1024) >> 6;
                int dd = col & 63;
                int bi = row0 / 2048;
                int kv = row0 % 2048;
                int kvs = kv_sigma(kv);
                *(u16x4*)&vt[(((size_t)bi * HEADS_ + hh) * 64 + dd) * 2048 +
                             kvs] = o4;
            }
        }
    }
}

// ---------------------------------------------------------------------------
// MFMA flash attention v7 (R13-proven): TWO 64-row q-groups per block share
// each staged K/V tile; grid 512 blocks; 3-buffer counted-vmcnt pipeline;
// zero-shuffle PV + ones-column lr; v_max3 tree; defer-max; exp2-domain
// softmax; cvt_pk packing; XCD swizzle.
// ---------------------------------------------------------------------------
template <int KLEN, int IS_SA>
__global__ __launch_bounds__(256) void attn_mfma3(
    const u16* __restrict__ Qsrc, const u16* __restrict__ Ksrc,
    const u16* __restrict__ Vtg, const int* __restrict__ mask,
    u16* __restrict__ O) {
    constexpr int QSTR = IS_SA ? 3 * INNER_ : INNER_;
    constexpr int KSTR = IS_SA ? 3 * INNER_ : 2 * INNER_;
    constexpr int KOFF = IS_SA ? INNER_ : 0;

    __shared__ __align__(16) u16 Ks[3][64 * 64];
    __shared__ __align__(16) u16 Vs[3][64 * 64];

    const int t = threadIdx.x;
    const int lane = t & 63, w = t >> 6;
    const int c = lane & 15, g = lane >> 4;

    const int nwg = gridDim.x;  // 512
    const int wid = (blockIdx.x & 7) * (nwg >> 3) + (blockIdx.x >> 3);
    const int qb = wid & 7;
    const int h  = (wid >> 3) & 15;
    const int bb = wid >> 7;
    const int q0 = qb * 128;
    const int kvbase = bb * KLEN;

    const u16* qp0 =
        Qsrc + (size_t)(bb * N_ + q0 + w * 16 + c) * QSTR + h * 64 + g * 8;
    const u16* qp1 = qp0 + (size_t)64 * QSTR;
    bf16x8 qf0[2], qf1[2];
    qf0[0] = *(const bf16x8*)qp0;
    qf0[1] = *(const bf16x8*)(qp0 + 32);
    qf1[0] = *(const bf16x8*)qp1;
    qf1[1] = *(const bf16x8*)(qp1 + 32);

    const int sl_r = lane >> 3;
    const int scol = ((lane & 7) ^ sl_r) * 8;
    const int r0 = w * 16, r1 = w * 16 + 8;
    const u16* kp0 = Ksrc + (size_t)(kvbase + r0 + sl_r) * KSTR + KOFF +
                     h * 64 + scol;
    const u16* kp1 = Ksrc + (size_t)(kvbase + r1 + sl_r) * KSTR + KOFF +
                     h * 64 + scol;
    const u16* vp0 =
        Vtg + ((size_t)(bb * HEADS_ + h) * 64 + r0 + sl_r) * KLEN + scol;
    const u16* vp1 =
        Vtg + ((size_t)(bb * HEADS_ + h) * 64 + r1 + sl_r) * KLEN + scol;
    const int* mp = mask + bb * N_ + lane;

    auto stageKV = [&](int buf) {
        GLOAD16(kp0, &Ks[buf][r0 * 64]);
        GLOAD16(kp1, &Ks[buf][r1 * 64]);
        GLOAD16(vp0, &Vs[buf][r0 * 64]);
        GLOAD16(vp1, &Vs[buf][r1 * 64]);
        kp0 += (size_t)64 * KSTR;
        kp1 += (size_t)64 * KSTR;
        vp0 += 64;
        vp1 += 64;
    };

    f32x4 o0[4] = {}, o1[4] = {};
    f32x4 oL0 = {}, oL1 = {};
    float mr0 = -1e30f, mr1 = -1e30f;
    const i32x4 onesI = {0x3F803F80, 0x3F803F80, 0x3F803F80, 0x3F803F80};
    const bf16x8 ones = *(const bf16x8*)&onesI;
    constexpr int NT = KLEN / 64;

    stageKV(0);
    stageKV(1);
    int cb = 0, sb = 2;

    for (int kt = 0; kt < NT; ++kt) {
        if (kt + 1 < NT)
            asm volatile("s_waitcnt vmcnt(4)" ::: "memory");
        else
            asm volatile("s_waitcnt vmcnt(0)" ::: "memory");
        __builtin_amdgcn_s_barrier();
        int mbit = 1;
        if constexpr (IS_SA) {
            mbit = *mp;
            mp += 64;
        }
        if (kt + 2 < NT) {
            stageKV(sb);
            sb = (sb == 2) ? 0 : sb + 1;
        }

        // S^T = K Q^T for both q-groups; K fragment loaded once
        f32x4 sv0[4] = {}, sv1[4] = {};
        #pragma unroll
        for (int kvb = 0; kvb < 4; ++kvb) {
            #pragma unroll
            for (int f = 0; f < 2; ++f) {
                bf16x8 kf = *(const bf16x8*)&Ks[cb][(kvb * 16 + c) * 64 +
                                                    (((g + 4 * f) ^ (c & 7)) * 8)];
                sv0[kvb] = __builtin_amdgcn_mfma_f32_16x16x32_bf16(
                    kf, qf0[f], sv0[kvb], 0, 0, 0);
                sv1[kvb] = __builtin_amdgcn_mfma_f32_16x16x32_bf16(
                    kf, qf1[f], sv1[kvb], 0, 0, 0);
            }
        }

        if constexpr (IS_SA) {
            unsigned long long ball = __ballot(mbit != 0);
            if (ball != ~0ull) {
                float negm_reg = mbit ? 0.f : 2.0e10f;
                #pragma unroll
                for (int kvb = 0; kvb < 4; ++kvb)
                    #pragma unroll
                    for (int r = 0; r < 4; ++r) {
                        float nm = __shfl(negm_reg, kvb * 16 + g * 4 + r);
                        sv0[kvb][r] -= nm;
                        sv1[kvb][r] -= nm;
                    }
            }
        }

        // local max per group (max3 tree)
        float a0 = max3f(sv0[0][0], sv0[0][1], sv0[0][2]);
        float a1 = max3f(sv0[0][3], sv0[1][0], sv0[1][1]);
        float a2 = max3f(sv0[1][2], sv0[1][3], sv0[2][0]);
        float a3 = max3f(sv0[2][1], sv0[2][2], sv0[2][3]);
        float a4 = max3f(sv0[3][0], sv0[3][1], sv0[3][2]);
        float tm0 = fmaxf(max3f(a0, a1, a2), max3f(a3, a4, sv0[3][3]));
        float b0 = max3f(sv1[0][0], sv1[0][1], sv1[0][2]);
        float b1 = max3f(sv1[0][3], sv1[1][0], sv1[1][1]);
        float b2 = max3f(sv1[1][2], sv1[1][3], sv1[2][0]);
        float b3 = max3f(sv1[2][1], sv1[2][2], sv1[2][3]);
        float b4 = max3f(sv1[3][0], sv1[3][1], sv1[3][2]);
        float tm1 = fmaxf(max3f(b0, b1, b2), max3f(b3, b4, sv1[3][3]));

        if (!__all(fmaxf(tm0 - mr0, tm1 - mr1) <= 8.0f)) {  // rare rescale
            float t0 = fmaxf(tm0, __shfl_xor(tm0, 16));
            t0 = fmaxf(t0, __shfl_xor(t0, 32));
            float t1 = fmaxf(tm1, __shfl_xor(tm1, 16));
            t1 = fmaxf(t1, __shfl_xor(t1, 32));
            float mn0 = fmaxf(mr0, t0), mn1 = fmaxf(mr1, t1);
            float c0 = exp2_fast(mr0 - mn0), c1 = exp2_fast(mr1 - mn1);
            mr0 = mn0; mr1 = mn1;
            float c0O[4], c1O[4];
            #pragma unroll
            for (int r = 0; r < 4; ++r) {
                c0O[r] = __shfl(c0, g * 4 + r);
                c1O[r] = __shfl(c1, g * 4 + r);
            }
            #pragma unroll
            for (int db = 0; db < 4; ++db)
                #pragma unroll
                for (int r = 0; r < 4; ++r) {
                    o0[db][r] *= c0O[r];
                    o1[db][r] *= c1O[r];
                }
            #pragma unroll
            for (int r = 0; r < 4; ++r) {
                oL0[r] *= c0O[r];
                oL1[r] *= c1O[r];
            }
        }

        #pragma unroll
        for (int kvb = 0; kvb < 4; ++kvb)
            #pragma unroll
            for (int r = 0; r < 4; ++r) {
                sv0[kvb][r] = exp2_fast(sv0[kvb][r] - mr0);
                sv1[kvb][r] = exp2_fast(sv1[kvb][r] - mr1);
            }

        unsigned pk0[4][2], pk1[4][2];
        #pragma unroll
        for (int kvb = 0; kvb < 4; ++kvb)
            #pragma unroll
            for (int j = 0; j < 2; ++j) {
                pk0[kvb][j] = cvt_pk_bf16(sv0[kvb][2 * j], sv0[kvb][2 * j + 1]);
                pk1[kvb][j] = cvt_pk_bf16(sv1[kvb][2 * j], sv1[kvb][2 * j + 1]);
            }

        // zero-shuffle PV + ones-column row-sum; V fragment loaded once
        #pragma unroll
        for (int pv = 0; pv < 2; ++pv) {
            i32x4 tw0 = {(int)pk0[2 * pv][0], (int)pk0[2 * pv][1],
                         (int)pk0[2 * pv + 1][0], (int)pk0[2 * pv + 1][1]};
            i32x4 tw1 = {(int)pk1[2 * pv][0], (int)pk1[2 * pv][1],
                         (int)pk1[2 * pv + 1][0], (int)pk1[2 * pv + 1][1]};
            bf16x8 pa0 = *(bf16x8*)&tw0;
            bf16x8 pa1 = *(bf16x8*)&tw1;
            oL0 = __builtin_amdgcn_mfma_f32_16x16x32_bf16(pa0, ones, oL0, 0, 0, 0);
            oL1 = __builtin_amdgcn_mfma_f32_16x16x32_bf16(pa1, ones, oL1, 0, 0, 0);
            #pragma unroll
            for (int db = 0; db < 4; ++db) {
                bf16x8 vf = *(const bf16x8*)&Vs[cb][(db * 16 + c) * 64 +
                                                    (((g + 4 * pv) ^ (c & 7)) * 8)];
                o0[db] = __builtin_amdgcn_mfma_f32_16x16x32_bf16(pa0, vf,
                                                                 o0[db], 0, 0, 0);
                o1[db] = __builtin_amdgcn_mfma_f32_16x16x32_bf16(pa1, vf,
                                                                 o1[db], 0, 0, 0);
            }
        }
        cb = (cb == 2) ? 0 : cb + 1;
    }

    float i0[4], i1[4];
    #pragma unroll
    for (int r = 0; r < 4; ++r) {
        i0[r] = rcp_fast(oL0[r]);
        i1[r] = rcp_fast(oL1[r]);
    }
    #pragma unroll
    for (int db = 0; db < 4; ++db)
        #pragma unroll
        for (int r = 0; r < 4; ++r) {
            size_t idx =
                (size_t)(bb * N_ + q0 + w * 16 + g * 4 + r) * INNER_ +
                h * 64 + db * 16 + c;
            O[idx] = f2bf(o0[db][r] * i0[r]);
            O[idx + (size_t)64 * INNER_] = f2bf(o1[db][r] * i1[r]);
        }
}

// ---------------------------------------------------------------------------
extern "C" void kernel_launch(void* const* d_in, const int* in_sizes, int n_in,
                              void* d_out, int out_size, void* d_ws,
                              size_t ws_size, hipStream_t stream) {
    const float* x     = (const float*)d_in[0];
    const float* ctx   = (const float*)d_in[1];
    const int*   mask  = (const int*)d_in[2];
    const float* ln_g  = (const float*)d_in[3];
    const float* ln_b  = (const float*)d_in[4];
    const float* Wqkv  = (const float*)d_in[5];
    const float* Wo_sa = (const float*)d_in[6];
    const float* bo_sa = (const float*)d_in[7];
    const float* Wkv   = (const float*)d_in[8];
    const float* Wq    = (const float*)d_in[9];
    const float* Wo_ca = (const float*)d_in[10];
    const float* bo_ca = (const float*)d_in[11];
    const float* W1    = (const float*)d_in[12];
    const float* b1    = (const float*)d_in[13];
    const float* W2    = (const float*)d_in[14];
    const float* b2    = (const float*)d_in[15];
    float* xout = (float*)d_out;

    char* ws = (char*)d_ws;
    u16* lnout = (u16*)ws;                        // 8MB (also attn out)
    u16* big   = (u16*)(ws + (8ull << 20));       // 32MB: qkv / kv / h1
    u16* qca   = (u16*)(ws + (40ull << 20));      // 8MB
    u16* ctxb  = (u16*)(ws + (48ull << 20));      // 16MB
    u16* wt    = (u16*)(ws + (64ull << 20));      // 32MB: transposed wts
    u16* xb    = (u16*)(ws + (96ull << 20));      // 8MB: bf16 residual stream
    u16* R1    = (u16*)(ws + (104ull << 20));     // 16MB: vt | d0+d1
    u16* aout  = lnout;

    // wt sub-offsets (elements)
    const int O_QKV = 0;
    const int O_WOSA = 3145728;
    const int O_WQ   = 4194304;
    const int O_WKV  = 5242880;
    const int O_WOCA = 7340032;
    const int O_W1   = 8388608;
    const int O_W2   = 12582912;

    const int ROWS = B_ * N_;    // 4096
    const int HALF = ROWS * DIM_;
    dim3 blk(256);

    // one dispatch casts both ctx (8M f32) and x (4M f32)
    cast2_kernel<<<(B_ * M_ * CTX_ + B_ * N_ * DIM_) / 1024, blk, 0, stream>>>(
        ctx, ctxb, B_ * M_ * CTX_ / 4, x, xb);

    for (int i = 0; i < DEPTH_; ++i) {
        const float* g  = ln_g + (size_t)(i * 3) * DIM_;
        const float* bb = ln_b + (size_t)(i * 3) * DIM_;

        PrepArgs pa;
        pa.src[0] = Wqkv  + (size_t)i * DIM_ * 3 * INNER_;
        pa.src[1] = Wo_sa + (size_t)i * INNER_ * DIM_;
        pa.src[2] = Wq    + (size_t)i * DIM_ * INNER_;
        pa.src[3] = Wkv   + (size_t)i * CTX_ * 2 * INNER_;
        pa.src[4] = Wo_ca + (size_t)i * INNER_ * DIM_;
        pa.src[5] = W1    + (size_t)i * DIM_ * MLP_;
        pa.src[6] = W2    + (size_t)i * MLP_ * DIM_;
        int Ks_[7] = {1024, 1024, 1024, 1024, 1024, 1024, 4096};
        int Ns_[7] = {3072, 1024, 1024, 2048, 1024, 4096, 1024};
        int Of_[7] = {O_QKV, O_WOSA, O_WQ, O_WKV, O_WOCA, O_W1, O_W2};
        int cum = 0;
        for (int k = 0; k < 7; ++k) {
            pa.K[k] = Ks_[k]; pa.N[k] = Ns_[k]; pa.dstOff[k] = Of_[k];
            cum += (Ks_[k] / 32) * (Ns_[k] / 32);
            pa.tileCum[k] = cum;
        }
        prep_weights<<<cum, blk, 0, stream>>>(pa, wt);

        // ---- self-attention ----
        if (i == 0)
            ln_res<0><<<ROWS, blk, 0, stream>>>(xb, nullptr, nullptr,
                                                nullptr, g, bb, lnout);
        else
            ln_res<1><<<ROWS, blk, 0, stream>>>(xb, R1, R1 + HALF,
                                                b2 + (size_t)(i - 1) * DIM_,
                                                g, bb, lnout);
        gemm_mfma3<4, 1><<<24 * 32, blk, 0, stream>>>(
            lnout, wt + O_QKV, nullptr, big, R1, ROWS, 3 * INNER_, DIM_,
            24, 32);
        attn_mfma3<N_, 1><<<512, blk, 0, stream>>>(big, big, R1, mask, aout);
        gemm_mfma3<0, 2><<<8 * 32 * 2, blk, 0, stream>>>(
            aout, wt + O_WOSA, nullptr, R1, nullptr, ROWS, DIM_, INNER_,
            8, 32);

        // ---- cross-attention ----
        ln_res<1><<<ROWS, blk, 0, stream>>>(xb, R1, R1 + HALF,
                                            bo_sa + (size_t)i * DIM_,
                                            g + DIM_, bb + DIM_, lnout);
        gemm_dual<<<1280, blk, 0, stream>>>(ctxb, wt + O_WKV, big, R1,
                                            lnout, wt + O_WQ, qca);
        attn_mfma3<M_, 0><<<512, blk, 0, stream>>>(qca, big, R1, mask, aout);
        gemm_mfma3<0, 2><<<8 * 32 * 2, blk, 0, stream>>>(
            aout, wt + O_WOCA, nullptr, R1, nullptr, ROWS, DIM_, INNER_,
            8, 32);

        // ---- feed-forward ----
        ln_res<1><<<ROWS, blk, 0, stream>>>(xb, R1, R1 + HALF,
                                            bo_ca + (size_t)i * DIM_,
                                            g + 2 * DIM_, bb + 2 * DIM_,
                                            lnout);
        gemm_mfma3<1, 1><<<32 * 32, blk, 0, stream>>>(
            lnout, wt + O_W1, b1 + (size_t)i * MLP_, big, nullptr, ROWS, MLP_,
            DIM_, 32, 32);
        gemm_mfma3<0, 2><<<8 * 32 * 2, blk, 0, stream>>>(
            big, wt + O_W2, nullptr, R1, nullptr, ROWS, DIM_, MLP_, 8, 32);
    }
    res_add<<<ROWS, blk, 0, stream>>>(xout, xb, R1, R1 + HALF,
                                      b2 + (size_t)(DEPTH_ - 1) * DIM_);
}